// Round 4
// baseline (451.896 us; speedup 1.0000x reference)
//
#include <hip/hip_runtime.h>

// GCN: B=256 blocks, N=512 nodes, D_IN=D_HID=256, D_OUT=128, 3 steps.
// Round-4 schedule:
//   k_wconv : W0,W1 -> bf16 transposed (tiny)
//   k_lin0  : Z0 = bf16(feat) @ W0 — reg-stages fp32 feat, computes nz in-staging
//   k_propf : X = relu(diag(1/rowsum) * (adj_raw @ Z)) — A-fragments loaded
//             DIRECTLY global->reg (no LDS for A), B double-buffered in LDS,
//             ONE barrier per kt; rowsum via MFMA with nz-broadcast B-frag.
//   k_linear: Z1 = X1 @ W1 (bf16 fast path, global_load_lds)
//   k_propf : X2
//   k_tail  : out = relu((a0/rowsum0 @ X2) @ W2) @ Wout   (associativity)

typedef __attribute__((ext_vector_type(8))) short short8;
typedef __attribute__((ext_vector_type(4))) float f32x4;

__device__ __forceinline__ unsigned short f2bf(float x) {
  unsigned u = __float_as_uint(x);
  unsigned r = u + 0x7fffu + ((u >> 16) & 1u);
  return (unsigned short)(r >> 16);
}
__device__ __forceinline__ float bf2f(unsigned short b) {
  return __uint_as_float(((unsigned)b) << 16);
}
// packed fp32 pair -> bf16x2 (RNE), single HW op
__device__ __forceinline__ unsigned pkbf(float lo, float hi) {
  unsigned r;
  asm("v_cvt_pk_bf16_f32 %0, %1, %2" : "=v"(r) : "v"(lo), "v"(hi));
  return r;
}
__device__ __forceinline__ short8 pack8(float4 a, float4 b) {
  union { unsigned u[4]; short8 s; } r;
  r.u[0] = pkbf(a.x, a.y); r.u[1] = pkbf(a.z, a.w);
  r.u[2] = pkbf(b.x, b.y); r.u[3] = pkbf(b.z, b.w);
  return r.s;
}

#define GLDS(g, l) __builtin_amdgcn_global_load_lds( \
    (const __attribute__((address_space(1))) void*)(g), \
    (__attribute__((address_space(3))) void*)(l), 16, 0, 0)

// XCD-chunked bijective swizzle for grid 2048 (cpx = 256, 8 XCDs)
__device__ __forceinline__ int swz2048(int bid) {
  return (bid & 7) * 256 + (bid >> 3);
}

// ---------------------------------------------------------------------------
// W0/W1 (256,256) fp32 -> Wt bf16 TRANSPOSED: Wt[s][n][k] = W_s[k][n]
__global__ void k_wconv(const float* __restrict__ W0, const float* __restrict__ W1,
                        unsigned short* __restrict__ Wt) {
  int s = blockIdx.x >> 8;
  int n = blockIdx.x & 255;
  int k = threadIdx.x;
  const float* W = s ? W1 : W0;
  Wt[(size_t)s * 65536 + n * 256 + k] = f2bf(W[(size_t)k * 256 + n]);
}

// ---------------------------------------------------------------------------
// bf16 fast-path MFMA mainloop (128x128 tile, BK=64, 4 waves as 2x2 of 64x64)
__device__ __forceinline__ void gemm_tile(
    const char* Ag, int ldaB, const char* Bg, int ldbB, int nkt,
    char* ldsA, char* ldsB, f32x4 acc[4][4], int wm, int wn, int lane, int tid) {
  for (int kt = 0; kt < nkt; ++kt) {
#pragma unroll
    for (int q = 0; q < 4; ++q) {
      int P = (q * 256 + tid) * 16;          // physical LDS byte (linear)
      int L = P ^ (((P >> 7) & 7) << 4);     // logical byte (involution)
      int row = L >> 7, cb = L & 127;
      GLDS(Ag + (size_t)row * ldaB + kt * 128 + cb, ldsA + P);
      GLDS(Bg + (size_t)row * ldbB + kt * 128 + cb, ldsB + P);
    }
    __syncthreads();
#pragma unroll
    for (int ks = 0; ks < 2; ++ks) {
      short8 af[4], bfr[4];
      int c = ks * 64 + ((lane >> 4) << 4);
#pragma unroll
      for (int m = 0; m < 4; ++m) {
        int row = wm * 64 + m * 16 + (lane & 15);
        af[m] = *(const short8*)(ldsA + ((row * 128 + c) ^ ((row & 7) << 4)));
      }
#pragma unroll
      for (int n = 0; n < 4; ++n) {
        int row = wn * 64 + n * 16 + (lane & 15);
        bfr[n] = *(const short8*)(ldsB + ((row * 128 + c) ^ ((row & 7) << 4)));
      }
#pragma unroll
      for (int m = 0; m < 4; ++m)
#pragma unroll
        for (int n = 0; n < 4; ++n)
          acc[m][n] = __builtin_amdgcn_mfma_f32_16x16x32_bf16(af[m], bfr[n], acc[m][n], 0, 0, 0);
    }
    __syncthreads();
  }
}

// ---------------------------------------------------------------------------
// Z0 = bf16(feat) @ W0, Zt transposed out; nz computed in-staging.
__global__ __launch_bounds__(256) void k_lin0(const float* __restrict__ feat,
                                              const unsigned short* __restrict__ Wt,
                                              unsigned short* __restrict__ Zt,
                                              float* __restrict__ nzOut) {
  __shared__ char ldsA[16384];
  __shared__ char ldsB[16384];
  int tid = threadIdx.x, lane = tid & 63, wid = tid >> 6;
  int wm = wid >> 1, wn = wid & 1;
  int tile = swz2048(blockIdx.x);
  int tm = tile >> 1, tn = tile & 1;
  const float* Ag = feat + (size_t)tm * 128 * 256;
  const char* Bg = (const char*)(Wt + (size_t)tn * 128 * 256);
  int r = tid >> 1, hk = tid & 1;
  const float* myrow = Ag + (size_t)r * 256 + hk * 32;
  float ssq = 0.f;
  f32x4 acc[4][4];
#pragma unroll
  for (int m = 0; m < 4; ++m)
#pragma unroll
    for (int n = 0; n < 4; ++n) { f32x4 z = {0.f, 0.f, 0.f, 0.f}; acc[m][n] = z; }

  for (int kt = 0; kt < 4; ++kt) {
#pragma unroll
    for (int q = 0; q < 4; ++q) {
      int P = (q * 256 + tid) * 16;
      int L = P ^ (((P >> 7) & 7) << 4);
      int row = L >> 7, cb = L & 127;
      GLDS(Bg + (size_t)row * 512 + kt * 128 + cb, ldsB + P);
    }
    float4 f[8];
#pragma unroll
    for (int q = 0; q < 8; ++q) f[q] = ((const float4*)(myrow + kt * 64))[q];
#pragma unroll
    for (int q = 0; q < 8; ++q)
      ssq += f[q].x * f[q].x + f[q].y * f[q].y + f[q].z * f[q].z + f[q].w * f[q].w;
#pragma unroll
    for (int q = 0; q < 4; ++q) {
      uint4 w;
      w.x = pkbf(f[2 * q].x, f[2 * q].y);
      w.y = pkbf(f[2 * q].z, f[2 * q].w);
      w.z = pkbf(f[2 * q + 1].x, f[2 * q + 1].y);
      w.w = pkbf(f[2 * q + 1].z, f[2 * q + 1].w);
      int cb = hk * 64 + q * 16;
      *(uint4*)(ldsA + ((r * 128 + cb) ^ ((r & 7) << 4))) = w;
    }
    __syncthreads();
#pragma unroll
    for (int ks = 0; ks < 2; ++ks) {
      short8 af[4], bfr[4];
      int c = ks * 64 + ((lane >> 4) << 4);
#pragma unroll
      for (int m = 0; m < 4; ++m) {
        int row = wm * 64 + m * 16 + (lane & 15);
        af[m] = *(const short8*)(ldsA + ((row * 128 + c) ^ ((row & 7) << 4)));
      }
#pragma unroll
      for (int n = 0; n < 4; ++n) {
        int row = wn * 64 + n * 16 + (lane & 15);
        bfr[n] = *(const short8*)(ldsB + ((row * 128 + c) ^ ((row & 7) << 4)));
      }
#pragma unroll
      for (int m = 0; m < 4; ++m)
#pragma unroll
        for (int n = 0; n < 4; ++n)
          acc[m][n] = __builtin_amdgcn_mfma_f32_16x16x32_bf16(af[m], bfr[n], acc[m][n], 0, 0, 0);
    }
    __syncthreads();
  }

  float tot = ssq + __shfl_xor(ssq, 1);
  if (hk == 0 && tn == 0) nzOut[(size_t)tm * 128 + r] = (tot > 0.f) ? 1.f : 0.f;

  int b = tm >> 2;
  int node_base = ((tm & 3) * 128) + wm * 64;
  int h_base = tn * 128 + wn * 64;
#pragma unroll
  for (int m = 0; m < 4; ++m) {
    int node = node_base + m * 16 + ((lane >> 4) << 2);
#pragma unroll
    for (int n = 0; n < 4; ++n) {
      int h = h_base + n * 16 + (lane & 15);
      f32x4 v = acc[m][n];
      ushort4 p;
      p.x = f2bf(v[0]); p.y = f2bf(v[1]); p.z = f2bf(v[2]); p.w = f2bf(v[3]);
      *(ushort4*)(Zt + ((size_t)b * 256 + h) * 512 + node) = p;
    }
  }
}

// ---------------------------------------------------------------------------
// X = relu(diag(1/rowsum) * (adj_raw @ Z)) per block: M=512, N=256, K=512.
// A-frags loaded DIRECTLY from fp32 global into registers (no LDS for A);
// B (Zt bf16) double-buffered in LDS via GLDS; ONE barrier per kt.
// rowsum = A@nz computed by MFMA (nz-broadcast B-frag). grid = 2048.
__global__ __launch_bounds__(256) void k_propf(const float* __restrict__ adj,
                                               const unsigned short* __restrict__ Zt,
                                               const float* __restrict__ nz,
                                               unsigned short* __restrict__ Xout) {
  __shared__ char ldsB[32768];   // 2 x 16 KB double buffer
  __shared__ char nzbfL[1024];
  int tid = threadIdx.x, lane = tid & 63, wid = tid >> 6;
  int wm = wid >> 1, wn = wid & 1;
  int tile = swz2048(blockIdx.x);
  int b = tile >> 3, tm = (tile >> 1) & 3, tn = tile & 1;
  const char* Bg = (const char*)(Zt + ((size_t)b * 256 + tn * 128) * 512);
  {
    float2 nv = ((const float2*)(nz + (size_t)b * 512))[tid];
    ((unsigned*)nzbfL)[tid] = pkbf(nv.x, nv.y);
  }
  int r0 = lane & 15, kq = lane >> 4;
  // per-lane A base: row (b*512 + tm*128 + wm*64 + r0), col kq*8
  const float* Aw = adj + ((size_t)(b * 512 + tm * 128 + wm * 64 + r0)) * 512 + kq * 8;

  f32x4 acc[4][4];
  f32x4 acc_rs[4];
#pragma unroll
  for (int m = 0; m < 4; ++m) {
    f32x4 z = {0.f, 0.f, 0.f, 0.f};
    acc_rs[m] = z;
#pragma unroll
    for (int n = 0; n < 4; ++n) acc[m][n] = z;
  }

  // fp32 A fragment staging regs, double-buffered by kt parity
  float4 fp[2][4][2][2];

#define STAGE_B(KT, BUF) do {                                            \
    _Pragma("unroll")                                                    \
    for (int q = 0; q < 4; ++q) {                                        \
      int P = (q * 256 + tid) * 16;                                      \
      int L = P ^ (((P >> 7) & 7) << 4);                                 \
      int row = L >> 7, cb = L & 127;                                    \
      GLDS(Bg + (size_t)row * 1024 + (KT) * 128 + cb,                    \
           ldsB + (BUF) * 16384 + P);                                    \
    } } while (0)

#define LOAD_A(KT, BUF) do {                                             \
    _Pragma("unroll")                                                    \
    for (int m = 0; m < 4; ++m)                                          \
      _Pragma("unroll")                                                  \
      for (int ks = 0; ks < 2; ++ks) {                                   \
        const float* p = Aw + (size_t)m * 16 * 512 + (KT) * 64 + ks * 32;\
        fp[BUF][m][ks][0] = *(const float4*)(p);                         \
        fp[BUF][m][ks][1] = *(const float4*)(p + 4);                     \
      } } while (0)

  // prologue: prefetch kt=0
  STAGE_B(0, 0);
  LOAD_A(0, 0);

#pragma unroll
  for (int kt = 0; kt < 8; ++kt) {
    __syncthreads();   // compiler drains vmcnt here: prefetches issued one
                       // full compute phase ago -> residual wait only
    int cur = kt & 1, nxt = (kt + 1) & 1;
    // convert current A frags fp32 -> bf16 (frees fp[cur])
    short8 af[4][2];
#pragma unroll
    for (int m = 0; m < 4; ++m)
#pragma unroll
      for (int ks = 0; ks < 2; ++ks)
        af[m][ks] = pack8(fp[cur][m][ks][0], fp[cur][m][ks][1]);
    // issue next-kt prefetches (hidden under the MFMA block below)
    if (kt < 7) {
      STAGE_B(kt + 1, nxt);
      LOAD_A(kt + 1, nxt);
    }
    // compute kt from ldsB[cur] + af
#pragma unroll
    for (int ks = 0; ks < 2; ++ks) {
      short8 bfr[4], nzf;
      int c = ks * 64 + (kq << 4);
      nzf = *(const short8*)(nzbfL + kt * 128 + c);
#pragma unroll
      for (int n = 0; n < 4; ++n) {
        int row = wn * 64 + n * 16 + r0;
        bfr[n] = *(const short8*)(ldsB + cur * 16384 + ((row * 128 + c) ^ ((row & 7) << 4)));
      }
#pragma unroll
      for (int m = 0; m < 4; ++m)
        acc_rs[m] = __builtin_amdgcn_mfma_f32_16x16x32_bf16(af[m][ks], nzf, acc_rs[m], 0, 0, 0);
#pragma unroll
      for (int m = 0; m < 4; ++m)
#pragma unroll
        for (int n = 0; n < 4; ++n)
          acc[m][n] = __builtin_amdgcn_mfma_f32_16x16x32_bf16(af[m][ks], bfr[n], acc[m][n], 0, 0, 0);
    }
  }
#undef STAGE_B
#undef LOAD_A

  int node_base = tm * 128 + wm * 64;
  int h_base = tn * 128 + wn * 64;
#pragma unroll
  for (int m = 0; m < 4; ++m) {
    int node = node_base + m * 16 + (kq << 2);
    float inv[4];
#pragma unroll
    for (int r2 = 0; r2 < 4; ++r2) {
      float rsv = acc_rs[m][r2];
      inv[r2] = 1.f / ((rsv == 0.f) ? 1.f : rsv);
    }
#pragma unroll
    for (int n = 0; n < 4; ++n) {
      int h = h_base + n * 16 + r0;
#pragma unroll
      for (int r2 = 0; r2 < 4; ++r2) {
        float v = acc[m][n][r2] * inv[r2];
        v = v > 0.f ? v : 0.f;
        Xout[((size_t)b * 512 + node + r2) * 256 + h] = f2bf(v);
      }
    }
  }
}

// ---------------------------------------------------------------------------
// Z = X @ W  (bf16 fast path). M=131072, N=256, K=256. grid = 2048.
__global__ __launch_bounds__(256) void k_linear(const unsigned short* __restrict__ X,
                                                const unsigned short* __restrict__ Wt,
                                                unsigned short* __restrict__ Zt) {
  __shared__ char lds[32768];
  int tid = threadIdx.x, lane = tid & 63, wid = tid >> 6;
  int wm = wid >> 1, wn = wid & 1;
  int tile = swz2048(blockIdx.x);
  int tm = tile >> 1, tn = tile & 1;
  const char* Ag = (const char*)(X + (size_t)tm * 128 * 256);
  const char* Bg = (const char*)(Wt + (size_t)tn * 128 * 256);
  f32x4 acc[4][4];
#pragma unroll
  for (int m = 0; m < 4; ++m)
#pragma unroll
    for (int n = 0; n < 4; ++n) { f32x4 z = {0.f, 0.f, 0.f, 0.f}; acc[m][n] = z; }
  gemm_tile(Ag, 512, Bg, 512, 4, lds, lds + 16384, acc, wm, wn, lane, tid);
  int b = tm >> 2;
  int node_base = ((tm & 3) * 128) + wm * 64;
  int h_base = tn * 128 + wn * 64;
#pragma unroll
  for (int m = 0; m < 4; ++m) {
    int node = node_base + m * 16 + ((lane >> 4) << 2);
#pragma unroll
    for (int n = 0; n < 4; ++n) {
      int h = h_base + n * 16 + (lane & 15);
      f32x4 v = acc[m][n];
      ushort4 p;
      p.x = f2bf(v[0]); p.y = f2bf(v[1]); p.z = f2bf(v[2]); p.w = f2bf(v[3]);
      *(ushort4*)(Zt + ((size_t)b * 256 + h) * 512 + node) = p;
    }
  }
}

// ---------------------------------------------------------------------------
// Tail (one block per batch-block b):
//   inv = 1/rowsum0 (from raw adj row 0 & nz) ; y = (a0*inv) @ X2 ;
//   x3 = relu(y @ W2) ; out = x3 @ Wout
__global__ __launch_bounds__(256) void k_tail(const float* __restrict__ adj,
                                              const unsigned short* __restrict__ X2,
                                              const float* __restrict__ nz,
                                              const float* __restrict__ W2,
                                              const float* __restrict__ Wout,
                                              float* __restrict__ out) {
  __shared__ float aL[512];
  __shared__ float red[4];
  __shared__ float sInv;
  __shared__ float yL[8][256];
  __shared__ float y[256];
  __shared__ float x3[256];
  int b = blockIdx.x, tid = threadIdx.x;
  {
    float2 av = ((const float2*)(adj + (size_t)b * 512 * 512))[tid];
    float2 nv = ((const float2*)(nz + (size_t)b * 512))[tid];
    aL[2 * tid] = av.x;
    aL[2 * tid + 1] = av.y;
    float p = av.x * nv.x + av.y * nv.y;
#pragma unroll
    for (int off = 1; off < 64; off <<= 1) p += __shfl_xor(p, off);
    if ((tid & 63) == 0) red[tid >> 6] = p;
  }
  __syncthreads();
  if (tid == 0) {
    float s = red[0] + red[1] + red[2] + red[3];
    sInv = 1.f / ((s == 0.f) ? 1.f : s);
  }
  __syncthreads();
  // phase 1: y[h] = inv * sum_j a0[j] * X2[j][h]
  {
    int hg = tid & 31, jg = tid >> 5;
    float acc8[8] = {0.f, 0.f, 0.f, 0.f, 0.f, 0.f, 0.f, 0.f};
    const unsigned short* Xb = X2 + (size_t)b * 512 * 256;
    for (int jj = 0; jj < 64; ++jj) {
      int j = jj * 8 + jg;
      short8 xv = *(const short8*)(Xb + (size_t)j * 256 + hg * 8);
      float a = aL[j];
#pragma unroll
      for (int r = 0; r < 8; ++r) acc8[r] += a * bf2f((unsigned short)xv[r]);
    }
#pragma unroll
    for (int r = 0; r < 8; ++r) yL[jg][hg * 8 + r] = acc8[r];
  }
  __syncthreads();
  {
    float s = 0.f;
#pragma unroll
    for (int g = 0; g < 8; ++g) s += yL[g][tid];
    y[tid] = s * sInv;
  }
  __syncthreads();
  // phase 2: x3[o] = relu(sum_k y[k] * W2[k][o])
  {
    float s = 0.f;
    for (int k = 0; k < 256; ++k) s += y[k] * W2[(size_t)k * 256 + tid];
    x3[tid] = s > 0.f ? s : 0.f;
  }
  __syncthreads();
  // phase 3: out[b][o] = sum_h x3[h] * Wout[h][o]
  if (tid < 128) {
    float s = 0.f;
    for (int h = 0; h < 256; ++h) s += x3[h] * Wout[(size_t)h * 128 + tid];
    out[(size_t)b * 128 + tid] = s;
  }
}

// ---------------------------------------------------------------------------
extern "C" void kernel_launch(void* const* d_in, const int* in_sizes, int n_in,
                              void* d_out, int out_size, void* d_ws, size_t ws_size,
                              hipStream_t stream) {
  (void)in_sizes; (void)n_in; (void)out_size; (void)ws_size;
  const float* feat = (const float*)d_in[0];
  const float* adj  = (const float*)d_in[1];
  const float* W0   = (const float*)d_in[2];
  const float* W1   = (const float*)d_in[3];
  const float* W2   = (const float*)d_in[4];
  const float* Wout = (const float*)d_in[5];
  float* out = (float*)d_out;

  char* ws = (char*)d_ws;
  unsigned short* Xbuf = (unsigned short*)(ws);                 //  67108864 B
  unsigned short* Zt   = (unsigned short*)(ws + 67108864);      //  67108864 B
  float* nzbuf         = (float*)(ws + 134217728);              //    524288 B
  unsigned short* Wt   = (unsigned short*)(ws + 134742016);     //    262144 B

  k_wconv<<<512, 256, 0, stream>>>(W0, W1, Wt);

  // step 0: fused feat-conversion linear (also writes nz), then propagation
  k_lin0<<<2048, 256, 0, stream>>>(feat, Wt, Zt, nzbuf);
  k_propf<<<2048, 256, 0, stream>>>(adj, Zt, nzbuf, Xbuf);
  // step 1
  k_linear<<<2048, 256, 0, stream>>>(Xbuf, Wt + 65536, Zt);
  k_propf<<<2048, 256, 0, stream>>>(adj, Zt, nzbuf, Xbuf);
  // step 2 (linear folded into tail via associativity) + output projection
  k_tail<<<256, 256, 0, stream>>>(adj, Xbuf, nzbuf, W2, Wout, out);
}

// Round 5
// 369.987 us; speedup vs baseline: 1.2214x; 1.2214x over previous
//
#include <hip/hip_runtime.h>

// GCN: B=256 blocks, N=512 nodes, D_IN=D_HID=256, D_OUT=128, 3 steps.
// Round-5 schedule (revert to round-2 dataflow + 8-wave 256x128 GEMM tiles):
//   k_wconv  : W0,W1 -> bf16 transposed (tiny)
//   k_lin0   : Z0 = bf16(feat) @ W0 — reg-stages fp32 feat, computes nz (round-3)
//   k_adj    : raw_adj fp32 -> adjN bf16 PRE-NORMALIZED by 1/rowsum (BW-peak)
//   k_prop8  : X = relu(adjN @ Z)   — 256x128 tile, 8 waves, GLDS staging
//   k_linear8: Z1 = X1 @ W1         — same template, nkt=4
//   k_prop8  : X2
//   k_tail   : out = relu((a0n @ X2) @ W2) @ Wout   (associativity, fp32 tail)

typedef __attribute__((ext_vector_type(8))) short short8;
typedef __attribute__((ext_vector_type(4))) float f32x4;

__device__ __forceinline__ unsigned short f2bf(float x) {
  unsigned u = __float_as_uint(x);
  unsigned r = u + 0x7fffu + ((u >> 16) & 1u);
  return (unsigned short)(r >> 16);
}
__device__ __forceinline__ float bf2f(unsigned short b) {
  return __uint_as_float(((unsigned)b) << 16);
}
// packed fp32 pair -> bf16x2 (RNE), single HW op
__device__ __forceinline__ unsigned pkbf(float lo, float hi) {
  unsigned r;
  asm("v_cvt_pk_bf16_f32 %0, %1, %2" : "=v"(r) : "v"(lo), "v"(hi));
  return r;
}

#define GLDS(g, l) __builtin_amdgcn_global_load_lds( \
    (const __attribute__((address_space(1))) void*)(g), \
    (__attribute__((address_space(3))) void*)(l), 16, 0, 0)

// XCD-chunked bijective swizzles
__device__ __forceinline__ int swz2048(int bid) { return (bid & 7) * 256 + (bid >> 3); }
__device__ __forceinline__ int swz1024(int bid) { return (bid & 7) * 128 + (bid >> 3); }

// ---------------------------------------------------------------------------
// W0/W1 (256,256) fp32 -> Wt bf16 TRANSPOSED: Wt[s][n][k] = W_s[k][n]
__global__ void k_wconv(const float* __restrict__ W0, const float* __restrict__ W1,
                        unsigned short* __restrict__ Wt) {
  int s = blockIdx.x >> 8;
  int n = blockIdx.x & 255;
  int k = threadIdx.x;
  const float* W = s ? W1 : W0;
  Wt[(size_t)s * 65536 + n * 256 + k] = f2bf(W[(size_t)k * 256 + n]);
}

// ---------------------------------------------------------------------------
// raw_adj (256,512,512) fp32 -> adjN bf16 normalized: adjN[i][j] = raw/rowsum
// rowsum = sum_j raw[i][j]*nz[j] (0 -> 1). One wave per adjacency row.
__global__ void k_adj(const float* __restrict__ adj, const float* __restrict__ nz,
                      unsigned short* __restrict__ adjN) {
  int row = blockIdx.x * 4 + (threadIdx.x >> 6);   // [0, 256*512)
  int lane = threadIdx.x & 63;
  int b = row >> 9;
  const float4* src = (const float4*)(adj + (size_t)row * 512);
  float4 a0 = src[lane * 2], a1 = src[lane * 2 + 1];
  const float4* nzp = (const float4*)(nz + (size_t)b * 512);
  float4 z0 = nzp[lane * 2], z1 = nzp[lane * 2 + 1];
  float s = a0.x * z0.x + a0.y * z0.y + a0.z * z0.z + a0.w * z0.w
          + a1.x * z1.x + a1.y * z1.y + a1.z * z1.z + a1.w * z1.w;
#pragma unroll
  for (int off = 1; off < 64; off <<= 1) s += __shfl_xor(s, off);
  float inv = 1.f / ((s == 0.f) ? 1.f : s);
  uint4 p;
  p.x = pkbf(a0.x * inv, a0.y * inv);
  p.y = pkbf(a0.z * inv, a0.w * inv);
  p.z = pkbf(a1.x * inv, a1.y * inv);
  p.w = pkbf(a1.z * inv, a1.w * inv);
  ((uint4*)(adjN + (size_t)row * 512))[lane] = p;
}

// ---------------------------------------------------------------------------
// Z0 = bf16(feat) @ W0, Zt transposed out; nz computed in-staging.
// M=131072, N=256, K=256. grid = 2048, 256 threads (round-3 proven).
__global__ __launch_bounds__(256) void k_lin0(const float* __restrict__ feat,
                                              const unsigned short* __restrict__ Wt,
                                              unsigned short* __restrict__ Zt,
                                              float* __restrict__ nzOut) {
  __shared__ char ldsA[16384];
  __shared__ char ldsB[16384];
  int tid = threadIdx.x, lane = tid & 63, wid = tid >> 6;
  int wm = wid >> 1, wn = wid & 1;
  int tile = swz2048(blockIdx.x);
  int tm = tile >> 1, tn = tile & 1;
  const float* Ag = feat + (size_t)tm * 128 * 256;
  const char* Bg = (const char*)(Wt + (size_t)tn * 128 * 256);
  int r = tid >> 1, hk = tid & 1;
  const float* myrow = Ag + (size_t)r * 256 + hk * 32;
  float ssq = 0.f;
  f32x4 acc[4][4];
#pragma unroll
  for (int m = 0; m < 4; ++m)
#pragma unroll
    for (int n = 0; n < 4; ++n) { f32x4 z = {0.f, 0.f, 0.f, 0.f}; acc[m][n] = z; }

  for (int kt = 0; kt < 4; ++kt) {
#pragma unroll
    for (int q = 0; q < 4; ++q) {
      int P = (q * 256 + tid) * 16;
      int L = P ^ (((P >> 7) & 7) << 4);
      int row = L >> 7, cb = L & 127;
      GLDS(Bg + (size_t)row * 512 + kt * 128 + cb, ldsB + P);
    }
    float4 f[8];
#pragma unroll
    for (int q = 0; q < 8; ++q) f[q] = ((const float4*)(myrow + kt * 64))[q];
#pragma unroll
    for (int q = 0; q < 8; ++q)
      ssq += f[q].x * f[q].x + f[q].y * f[q].y + f[q].z * f[q].z + f[q].w * f[q].w;
#pragma unroll
    for (int q = 0; q < 4; ++q) {
      uint4 w;
      w.x = pkbf(f[2 * q].x, f[2 * q].y);
      w.y = pkbf(f[2 * q].z, f[2 * q].w);
      w.z = pkbf(f[2 * q + 1].x, f[2 * q + 1].y);
      w.w = pkbf(f[2 * q + 1].z, f[2 * q + 1].w);
      int cb = hk * 64 + q * 16;
      *(uint4*)(ldsA + ((r * 128 + cb) ^ ((r & 7) << 4))) = w;
    }
    __syncthreads();
#pragma unroll
    for (int ks = 0; ks < 2; ++ks) {
      short8 af[4], bfr[4];
      int c = ks * 64 + ((lane >> 4) << 4);
#pragma unroll
      for (int m = 0; m < 4; ++m) {
        int row = wm * 64 + m * 16 + (lane & 15);
        af[m] = *(const short8*)(ldsA + ((row * 128 + c) ^ ((row & 7) << 4)));
      }
#pragma unroll
      for (int n = 0; n < 4; ++n) {
        int row = wn * 64 + n * 16 + (lane & 15);
        bfr[n] = *(const short8*)(ldsB + ((row * 128 + c) ^ ((row & 7) << 4)));
      }
#pragma unroll
      for (int m = 0; m < 4; ++m)
#pragma unroll
        for (int n = 0; n < 4; ++n)
          acc[m][n] = __builtin_amdgcn_mfma_f32_16x16x32_bf16(af[m], bfr[n], acc[m][n], 0, 0, 0);
    }
    __syncthreads();
  }

  float tot = ssq + __shfl_xor(ssq, 1);
  if (hk == 0 && tn == 0) nzOut[(size_t)tm * 128 + r] = (tot > 0.f) ? 1.f : 0.f;

  int b = tm >> 2;
  int node_base = ((tm & 3) * 128) + wm * 64;
  int h_base = tn * 128 + wn * 64;
#pragma unroll
  for (int m = 0; m < 4; ++m) {
    int node = node_base + m * 16 + ((lane >> 4) << 2);
#pragma unroll
    for (int n = 0; n < 4; ++n) {
      int h = h_base + n * 16 + (lane & 15);
      f32x4 v = acc[m][n];
      ushort4 p;
      p.x = f2bf(v[0]); p.y = f2bf(v[1]); p.z = f2bf(v[2]); p.w = f2bf(v[3]);
      *(ushort4*)(Zt + ((size_t)b * 256 + h) * 512 + node) = p;
    }
  }
}

// ---------------------------------------------------------------------------
// X = relu(adjN[b] @ Z[b])  per block: M=512, N=256, K=512.
// 256x128 tile, 8 waves (4x2 of 64x64), GLDS staging, m97 2-barrier loop.
// grid = 256 b x 2 tm x 2 tn = 1024, 512 threads.
__global__ __launch_bounds__(512, 4) void k_prop8(const unsigned short* __restrict__ adjN,
                                                  const unsigned short* __restrict__ Zt,
                                                  unsigned short* __restrict__ Xout) {
  __shared__ char ldsA[32768];   // 256 rows x 64 k x bf16
  __shared__ char ldsB[16384];   // 128 rows x 64 k x bf16
  int tid = threadIdx.x, lane = tid & 63, wid = tid >> 6;
  int wm = wid >> 1, wn = wid & 1;          // wm 0..3, wn 0..1
  int r0 = lane & 15, kq = lane >> 4;
  int tile = swz1024(blockIdx.x);
  int b = tile >> 2, tm = (tile >> 1) & 1, tn = tile & 1;
  const char* Ag = (const char*)(adjN + ((size_t)b * 512 + tm * 256) * 512);
  const char* Bg = (const char*)(Zt + ((size_t)b * 256 + tn * 128) * 512);
  f32x4 acc[4][4];
#pragma unroll
  for (int m = 0; m < 4; ++m)
#pragma unroll
    for (int n = 0; n < 4; ++n) { f32x4 z = {0.f, 0.f, 0.f, 0.f}; acc[m][n] = z; }

  for (int kt = 0; kt < 8; ++kt) {
#pragma unroll
    for (int q = 0; q < 4; ++q) {           // A: 32 KB
      int P = (q * 512 + tid) * 16;
      int L = P ^ (((P >> 7) & 7) << 4);
      int row = L >> 7, cb = L & 127;
      GLDS(Ag + (size_t)row * 1024 + kt * 128 + cb, ldsA + P);
    }
#pragma unroll
    for (int q = 0; q < 2; ++q) {           // B: 16 KB
      int P = (q * 512 + tid) * 16;
      int L = P ^ (((P >> 7) & 7) << 4);
      int row = L >> 7, cb = L & 127;
      GLDS(Bg + (size_t)row * 1024 + kt * 128 + cb, ldsB + P);
    }
    __syncthreads();
#pragma unroll
    for (int ks = 0; ks < 2; ++ks) {
      short8 af[4], bfr[4];
      int c = ks * 64 + (kq << 4);
#pragma unroll
      for (int m = 0; m < 4; ++m) {
        int row = wm * 64 + m * 16 + r0;
        af[m] = *(const short8*)(ldsA + ((row * 128 + c) ^ ((row & 7) << 4)));
      }
#pragma unroll
      for (int n = 0; n < 4; ++n) {
        int row = wn * 64 + n * 16 + r0;
        bfr[n] = *(const short8*)(ldsB + ((row * 128 + c) ^ ((row & 7) << 4)));
      }
#pragma unroll
      for (int m = 0; m < 4; ++m)
#pragma unroll
        for (int n = 0; n < 4; ++n)
          acc[m][n] = __builtin_amdgcn_mfma_f32_16x16x32_bf16(af[m], bfr[n], acc[m][n], 0, 0, 0);
    }
    __syncthreads();
  }

  int node_base = tm * 256 + wm * 64;
  int h_base = tn * 128 + wn * 64;
#pragma unroll
  for (int m = 0; m < 4; ++m) {
    int node = node_base + m * 16 + (kq << 2);
#pragma unroll
    for (int n = 0; n < 4; ++n) {
      int h = h_base + n * 16 + r0;
#pragma unroll
      for (int r2 = 0; r2 < 4; ++r2) {
        float v = acc[m][n][r2];
        v = v > 0.f ? v : 0.f;
        Xout[((size_t)b * 512 + node + r2) * 256 + h] = f2bf(v);
      }
    }
  }
}

// ---------------------------------------------------------------------------
// Z = X @ W  (M=131072, N=256, K=256), Zt transposed out.
// Same 256x128/8-wave template, nkt=4. grid = 512 tmg x 2 tn = 1024.
__global__ __launch_bounds__(512, 4) void k_linear8(const unsigned short* __restrict__ X,
                                                    const unsigned short* __restrict__ Wt,
                                                    unsigned short* __restrict__ Zt) {
  __shared__ char ldsA[32768];
  __shared__ char ldsB[16384];
  int tid = threadIdx.x, lane = tid & 63, wid = tid >> 6;
  int wm = wid >> 1, wn = wid & 1;
  int r0 = lane & 15, kq = lane >> 4;
  int tile = swz1024(blockIdx.x);
  int tmg = tile >> 1, tn = tile & 1;
  const char* Ag = (const char*)(X + (size_t)tmg * 256 * 256);
  const char* Bg = (const char*)(Wt + (size_t)tn * 128 * 256);
  f32x4 acc[4][4];
#pragma unroll
  for (int m = 0; m < 4; ++m)
#pragma unroll
    for (int n = 0; n < 4; ++n) { f32x4 z = {0.f, 0.f, 0.f, 0.f}; acc[m][n] = z; }

  for (int kt = 0; kt < 4; ++kt) {
#pragma unroll
    for (int q = 0; q < 4; ++q) {           // A: 32 KB
      int P = (q * 512 + tid) * 16;
      int L = P ^ (((P >> 7) & 7) << 4);
      int row = L >> 7, cb = L & 127;
      GLDS(Ag + (size_t)row * 512 + kt * 128 + cb, ldsA + P);
    }
#pragma unroll
    for (int q = 0; q < 2; ++q) {           // B: 16 KB
      int P = (q * 512 + tid) * 16;
      int L = P ^ (((P >> 7) & 7) << 4);
      int row = L >> 7, cb = L & 127;
      GLDS(Bg + (size_t)row * 512 + kt * 128 + cb, ldsB + P);
    }
    __syncthreads();
#pragma unroll
    for (int ks = 0; ks < 2; ++ks) {
      short8 af[4], bfr[4];
      int c = ks * 64 + (kq << 4);
#pragma unroll
      for (int m = 0; m < 4; ++m) {
        int row = wm * 64 + m * 16 + r0;
        af[m] = *(const short8*)(ldsA + ((row * 128 + c) ^ ((row & 7) << 4)));
      }
#pragma unroll
      for (int n = 0; n < 4; ++n) {
        int row = wn * 64 + n * 16 + r0;
        bfr[n] = *(const short8*)(ldsB + ((row * 128 + c) ^ ((row & 7) << 4)));
      }
#pragma unroll
      for (int m = 0; m < 4; ++m)
#pragma unroll
        for (int n = 0; n < 4; ++n)
          acc[m][n] = __builtin_amdgcn_mfma_f32_16x16x32_bf16(af[m], bfr[n], acc[m][n], 0, 0, 0);
    }
    __syncthreads();
  }

  int h_base = tn * 128 + wn * 64;
#pragma unroll
  for (int m = 0; m < 4; ++m) {
    int row = tmg * 256 + wm * 64 + m * 16 + (kq << 2);
    int b = row >> 9, node = row & 511;
#pragma unroll
    for (int n = 0; n < 4; ++n) {
      int h = h_base + n * 16 + r0;
      f32x4 v = acc[m][n];
      ushort4 p;
      p.x = f2bf(v[0]); p.y = f2bf(v[1]); p.z = f2bf(v[2]); p.w = f2bf(v[3]);
      *(ushort4*)(Zt + ((size_t)b * 256 + h) * 512 + node) = p;
    }
  }
}

// ---------------------------------------------------------------------------
// Tail (one block per batch-block b), round-2 proven version:
//   y = a0n @ X2_b (bf16 in, fp32 acc); x3 = relu(y @ W2); out = x3 @ Wout
__global__ __launch_bounds__(256) void k_tail(const unsigned short* __restrict__ adjN,
                                              const unsigned short* __restrict__ X2,
                                              const float* __restrict__ W2,
                                              const float* __restrict__ Wout,
                                              float* __restrict__ out) {
  __shared__ float aL[512];
  __shared__ float yL[8][256];
  __shared__ float y[256];
  __shared__ float x3[256];
  int b = blockIdx.x, tid = threadIdx.x;
  {
    const unsigned short* a0 = adjN + (size_t)b * 512 * 512;  // row 0 of block b
    ushort2 v = ((const ushort2*)a0)[tid];
    aL[tid * 2] = bf2f(v.x);
    aL[tid * 2 + 1] = bf2f(v.y);
  }
  __syncthreads();
  {
    int hg = tid & 31, jg = tid >> 5;
    float acc8[8] = {0.f, 0.f, 0.f, 0.f, 0.f, 0.f, 0.f, 0.f};
    const unsigned short* Xb = X2 + (size_t)b * 512 * 256;
    for (int jj = 0; jj < 64; ++jj) {
      int j = jj * 8 + jg;
      short8 xv = *(const short8*)(Xb + (size_t)j * 256 + hg * 8);
      float a = aL[j];
#pragma unroll
      for (int r = 0; r < 8; ++r) acc8[r] += a * bf2f((unsigned short)xv[r]);
    }
#pragma unroll
    for (int r = 0; r < 8; ++r) yL[jg][hg * 8 + r] = acc8[r];
  }
  __syncthreads();
  {
    float s = 0.f;
#pragma unroll
    for (int g = 0; g < 8; ++g) s += yL[g][tid];
    y[tid] = s;
  }
  __syncthreads();
  {
    float s = 0.f;
    for (int k = 0; k < 256; ++k) s += y[k] * W2[(size_t)k * 256 + tid];
    x3[tid] = s > 0.f ? s : 0.f;
  }
  __syncthreads();
  if (tid < 128) {
    float s = 0.f;
    for (int h = 0; h < 256; ++h) s += x3[h] * Wout[(size_t)h * 128 + tid];
    out[(size_t)b * 128 + tid] = s;
  }
}

// ---------------------------------------------------------------------------
extern "C" void kernel_launch(void* const* d_in, const int* in_sizes, int n_in,
                              void* d_out, int out_size, void* d_ws, size_t ws_size,
                              hipStream_t stream) {
  (void)in_sizes; (void)n_in; (void)out_size; (void)ws_size;
  const float* feat = (const float*)d_in[0];
  const float* adj  = (const float*)d_in[1];
  const float* W0   = (const float*)d_in[2];
  const float* W1   = (const float*)d_in[3];
  const float* W2   = (const float*)d_in[4];
  const float* Wout = (const float*)d_in[5];
  float* out = (float*)d_out;

  char* ws = (char*)d_ws;
  unsigned short* adjN = (unsigned short*)(ws);                 // 134217728 B
  unsigned short* Xbuf = (unsigned short*)(ws + 134217728);     //  67108864 B
  unsigned short* Zt   = (unsigned short*)(ws + 201326592);     //  67108864 B
  float* nzbuf         = (float*)(ws + 268435456);              //    524288 B
  unsigned short* Wt   = (unsigned short*)(ws + 268959744);     //    262144 B

  k_wconv<<<512, 256, 0, stream>>>(W0, W1, Wt);
  // step 0 linear (fused feat conversion, also writes nz)
  k_lin0<<<2048, 256, 0, stream>>>(feat, Wt, Zt, nzbuf);
  // adjacency conversion + normalization (needs nz)
  k_adj<<<32768, 256, 0, stream>>>(adj, nzbuf, adjN);
  // step 0 propagation
  k_prop8<<<1024, 512, 0, stream>>>(adjN, Zt, Xbuf);
  // step 1
  k_linear8<<<1024, 512, 0, stream>>>(Xbuf, Wt + 65536, Zt);
  k_prop8<<<1024, 512, 0, stream>>>(adjN, Zt, Xbuf);
  // step 2 (linear folded into tail via associativity) + output projection
  k_tail<<<256, 256, 0, stream>>>(adjN, Xbuf, W2, Wout, out);
}

// Round 6
// 342.214 us; speedup vs baseline: 1.3205x; 1.0812x over previous
//
#include <hip/hip_runtime.h>

// GCN: B=256 blocks, N=512 nodes, D_IN=D_HID=256, D_OUT=128, 3 steps.
// Round-6 = known-best composition (round-2 dataflow + round-3 lin0 fusion):
//   k_wconv : W0,W1 -> bf16 transposed (tiny)
//   k_lin0  : Z0 = bf16(feat) @ W0 — reg-stages fp32 feat, computes nz in-staging
//   k_adj   : raw_adj fp32 -> adjN bf16 PRE-NORMALIZED by 1/rowsum (BW-peak)
//   k_prop  : X = relu(adjN @ Z)   — 128x128 tile, 4 waves, GLDS staging (m97)
//   k_linear: Z1 = X1 @ W1         — same template, nkt=4
//   k_prop  : X2
//   k_tail  : out = relu((a0n @ X2) @ W2) @ Wout   (associativity, fp32 tail)

typedef __attribute__((ext_vector_type(8))) short short8;
typedef __attribute__((ext_vector_type(4))) float f32x4;

__device__ __forceinline__ unsigned short f2bf(float x) {
  unsigned u = __float_as_uint(x);
  unsigned r = u + 0x7fffu + ((u >> 16) & 1u);
  return (unsigned short)(r >> 16);
}
__device__ __forceinline__ float bf2f(unsigned short b) {
  return __uint_as_float(((unsigned)b) << 16);
}
// packed fp32 pair -> bf16x2 (RNE), single HW op
__device__ __forceinline__ unsigned pkbf(float lo, float hi) {
  unsigned r;
  asm("v_cvt_pk_bf16_f32 %0, %1, %2" : "=v"(r) : "v"(lo), "v"(hi));
  return r;
}

#define GLDS(g, l) __builtin_amdgcn_global_load_lds( \
    (const __attribute__((address_space(1))) void*)(g), \
    (__attribute__((address_space(3))) void*)(l), 16, 0, 0)

// XCD-chunked bijective swizzle for grid 2048 (cpx = 256, 8 XCDs)
__device__ __forceinline__ int swz2048(int bid) { return (bid & 7) * 256 + (bid >> 3); }

// ---------------------------------------------------------------------------
// W0/W1 (256,256) fp32 -> Wt bf16 TRANSPOSED: Wt[s][n][k] = W_s[k][n]
__global__ void k_wconv(const float* __restrict__ W0, const float* __restrict__ W1,
                        unsigned short* __restrict__ Wt) {
  int s = blockIdx.x >> 8;
  int n = blockIdx.x & 255;
  int k = threadIdx.x;
  const float* W = s ? W1 : W0;
  Wt[(size_t)s * 65536 + n * 256 + k] = f2bf(W[(size_t)k * 256 + n]);
}

// ---------------------------------------------------------------------------
// raw_adj (256,512,512) fp32 -> adjN bf16 normalized: adjN[i][j] = raw/rowsum
// rowsum = sum_j raw[i][j]*nz[j] (0 -> 1). One wave per adjacency row.
__global__ void k_adj(const float* __restrict__ adj, const float* __restrict__ nz,
                      unsigned short* __restrict__ adjN) {
  int row = blockIdx.x * 4 + (threadIdx.x >> 6);   // [0, 256*512)
  int lane = threadIdx.x & 63;
  int b = row >> 9;
  const float4* src = (const float4*)(adj + (size_t)row * 512);
  float4 a0 = src[lane * 2], a1 = src[lane * 2 + 1];
  const float4* nzp = (const float4*)(nz + (size_t)b * 512);
  float4 z0 = nzp[lane * 2], z1 = nzp[lane * 2 + 1];
  float s = a0.x * z0.x + a0.y * z0.y + a0.z * z0.z + a0.w * z0.w
          + a1.x * z1.x + a1.y * z1.y + a1.z * z1.z + a1.w * z1.w;
#pragma unroll
  for (int off = 1; off < 64; off <<= 1) s += __shfl_xor(s, off);
  float inv = 1.f / ((s == 0.f) ? 1.f : s);
  uint4 p;
  p.x = pkbf(a0.x * inv, a0.y * inv);
  p.y = pkbf(a0.z * inv, a0.w * inv);
  p.z = pkbf(a1.x * inv, a1.y * inv);
  p.w = pkbf(a1.z * inv, a1.w * inv);
  ((uint4*)(adjN + (size_t)row * 512))[lane] = p;
}

// ---------------------------------------------------------------------------
// bf16 fast-path MFMA mainloop (128x128 tile, BK=64, 4 waves as 2x2 of 64x64)
// A,B bf16 row-major [rows][K]; LDS XOR swizzle byte ^= ((row&7)<<4).
__device__ __forceinline__ void gemm_tile(
    const char* Ag, int ldaB, const char* Bg, int ldbB, int nkt,
    char* ldsA, char* ldsB, f32x4 acc[4][4], int wm, int wn, int lane, int tid) {
  for (int kt = 0; kt < nkt; ++kt) {
#pragma unroll
    for (int q = 0; q < 4; ++q) {
      int P = (q * 256 + tid) * 16;          // physical LDS byte (linear)
      int L = P ^ (((P >> 7) & 7) << 4);     // logical byte (involution)
      int row = L >> 7, cb = L & 127;
      GLDS(Ag + (size_t)row * ldaB + kt * 128 + cb, ldsA + P);
      GLDS(Bg + (size_t)row * ldbB + kt * 128 + cb, ldsB + P);
    }
    __syncthreads();
#pragma unroll
    for (int ks = 0; ks < 2; ++ks) {
      short8 af[4], bfr[4];
      int c = ks * 64 + ((lane >> 4) << 4);
#pragma unroll
      for (int m = 0; m < 4; ++m) {
        int row = wm * 64 + m * 16 + (lane & 15);
        af[m] = *(const short8*)(ldsA + ((row * 128 + c) ^ ((row & 7) << 4)));
      }
#pragma unroll
      for (int n = 0; n < 4; ++n) {
        int row = wn * 64 + n * 16 + (lane & 15);
        bfr[n] = *(const short8*)(ldsB + ((row * 128 + c) ^ ((row & 7) << 4)));
      }
#pragma unroll
      for (int m = 0; m < 4; ++m)
#pragma unroll
        for (int n = 0; n < 4; ++n)
          acc[m][n] = __builtin_amdgcn_mfma_f32_16x16x32_bf16(af[m], bfr[n], acc[m][n], 0, 0, 0);
    }
    __syncthreads();
  }
}

// ---------------------------------------------------------------------------
// Z0 = bf16(feat) @ W0, Zt transposed out; nz computed in-staging.
// M=131072, N=256, K=256. grid = 2048, 256 threads (round-3 proven).
__global__ __launch_bounds__(256) void k_lin0(const float* __restrict__ feat,
                                              const unsigned short* __restrict__ Wt,
                                              unsigned short* __restrict__ Zt,
                                              float* __restrict__ nzOut) {
  __shared__ char ldsA[16384];
  __shared__ char ldsB[16384];
  int tid = threadIdx.x, lane = tid & 63, wid = tid >> 6;
  int wm = wid >> 1, wn = wid & 1;
  int tile = swz2048(blockIdx.x);
  int tm = tile >> 1, tn = tile & 1;
  const float* Ag = feat + (size_t)tm * 128 * 256;
  const char* Bg = (const char*)(Wt + (size_t)tn * 128 * 256);
  int r = tid >> 1, hk = tid & 1;
  const float* myrow = Ag + (size_t)r * 256 + hk * 32;
  float ssq = 0.f;
  f32x4 acc[4][4];
#pragma unroll
  for (int m = 0; m < 4; ++m)
#pragma unroll
    for (int n = 0; n < 4; ++n) { f32x4 z = {0.f, 0.f, 0.f, 0.f}; acc[m][n] = z; }

  for (int kt = 0; kt < 4; ++kt) {
#pragma unroll
    for (int q = 0; q < 4; ++q) {
      int P = (q * 256 + tid) * 16;
      int L = P ^ (((P >> 7) & 7) << 4);
      int row = L >> 7, cb = L & 127;
      GLDS(Bg + (size_t)row * 512 + kt * 128 + cb, ldsB + P);
    }
    float4 f[8];
#pragma unroll
    for (int q = 0; q < 8; ++q) f[q] = ((const float4*)(myrow + kt * 64))[q];
#pragma unroll
    for (int q = 0; q < 8; ++q)
      ssq += f[q].x * f[q].x + f[q].y * f[q].y + f[q].z * f[q].z + f[q].w * f[q].w;
#pragma unroll
    for (int q = 0; q < 4; ++q) {
      uint4 w;
      w.x = pkbf(f[2 * q].x, f[2 * q].y);
      w.y = pkbf(f[2 * q].z, f[2 * q].w);
      w.z = pkbf(f[2 * q + 1].x, f[2 * q + 1].y);
      w.w = pkbf(f[2 * q + 1].z, f[2 * q + 1].w);
      int cb = hk * 64 + q * 16;
      *(uint4*)(ldsA + ((r * 128 + cb) ^ ((r & 7) << 4))) = w;
    }
    __syncthreads();
#pragma unroll
    for (int ks = 0; ks < 2; ++ks) {
      short8 af[4], bfr[4];
      int c = ks * 64 + ((lane >> 4) << 4);
#pragma unroll
      for (int m = 0; m < 4; ++m) {
        int row = wm * 64 + m * 16 + (lane & 15);
        af[m] = *(const short8*)(ldsA + ((row * 128 + c) ^ ((row & 7) << 4)));
      }
#pragma unroll
      for (int n = 0; n < 4; ++n) {
        int row = wn * 64 + n * 16 + (lane & 15);
        bfr[n] = *(const short8*)(ldsB + ((row * 128 + c) ^ ((row & 7) << 4)));
      }
#pragma unroll
      for (int m = 0; m < 4; ++m)
#pragma unroll
        for (int n = 0; n < 4; ++n)
          acc[m][n] = __builtin_amdgcn_mfma_f32_16x16x32_bf16(af[m], bfr[n], acc[m][n], 0, 0, 0);
    }
    __syncthreads();
  }

  float tot = ssq + __shfl_xor(ssq, 1);
  if (hk == 0 && tn == 0) nzOut[(size_t)tm * 128 + r] = (tot > 0.f) ? 1.f : 0.f;

  int b = tm >> 2;
  int node_base = ((tm & 3) * 128) + wm * 64;
  int h_base = tn * 128 + wn * 64;
#pragma unroll
  for (int m = 0; m < 4; ++m) {
    int node = node_base + m * 16 + ((lane >> 4) << 2);
#pragma unroll
    for (int n = 0; n < 4; ++n) {
      int h = h_base + n * 16 + (lane & 15);
      f32x4 v = acc[m][n];
      ushort4 p;
      p.x = f2bf(v[0]); p.y = f2bf(v[1]); p.z = f2bf(v[2]); p.w = f2bf(v[3]);
      *(ushort4*)(Zt + ((size_t)b * 256 + h) * 512 + node) = p;
    }
  }
}

// ---------------------------------------------------------------------------
// X = relu(adjN[b] @ Z[b])  (per block: M=512, N=256, K=512). grid = 2048.
__global__ __launch_bounds__(256) void k_prop(const unsigned short* __restrict__ adjN,
                                              const unsigned short* __restrict__ Zt,
                                              unsigned short* __restrict__ Xout) {
  __shared__ char lds[32768];
  int tid = threadIdx.x, lane = tid & 63, wid = tid >> 6;
  int wm = wid >> 1, wn = wid & 1;
  int tile = swz2048(blockIdx.x);
  int b = tile >> 3, tm = (tile >> 1) & 3, tn = tile & 1;
  const char* Ag = (const char*)(adjN + ((size_t)b * 512 + tm * 128) * 512);
  const char* Bg = (const char*)(Zt + ((size_t)b * 256 + tn * 128) * 512);
  f32x4 acc[4][4];
#pragma unroll
  for (int m = 0; m < 4; ++m)
#pragma unroll
    for (int n = 0; n < 4; ++n) { f32x4 z = {0.f, 0.f, 0.f, 0.f}; acc[m][n] = z; }
  gemm_tile(Ag, 1024, Bg, 1024, 8, lds, lds + 16384, acc, wm, wn, lane, tid);
  int node_base = tm * 128 + wm * 64;
  int h_base = tn * 128 + wn * 64;
#pragma unroll
  for (int m = 0; m < 4; ++m) {
    int node = node_base + m * 16 + ((lane >> 4) << 2);
#pragma unroll
    for (int n = 0; n < 4; ++n) {
      int h = h_base + n * 16 + (lane & 15);
#pragma unroll
      for (int r = 0; r < 4; ++r) {
        float v = acc[m][n][r];
        v = v > 0.f ? v : 0.f;
        Xout[((size_t)b * 512 + node + r) * 256 + h] = f2bf(v);
      }
    }
  }
}

// ---------------------------------------------------------------------------
// Z = X @ W  (M=131072, N=256, K=256), Zt transposed out. grid = 2048.
__global__ __launch_bounds__(256) void k_linear(const unsigned short* __restrict__ X,
                                                const unsigned short* __restrict__ Wt,
                                                unsigned short* __restrict__ Zt) {
  __shared__ char lds[32768];
  int tid = threadIdx.x, lane = tid & 63, wid = tid >> 6;
  int wm = wid >> 1, wn = wid & 1;
  int tile = swz2048(blockIdx.x);
  int tm = tile >> 1, tn = tile & 1;
  const char* Ag = (const char*)(X + (size_t)tm * 128 * 256);
  const char* Bg = (const char*)(Wt + (size_t)tn * 128 * 256);
  f32x4 acc[4][4];
#pragma unroll
  for (int m = 0; m < 4; ++m)
#pragma unroll
    for (int n = 0; n < 4; ++n) { f32x4 z = {0.f, 0.f, 0.f, 0.f}; acc[m][n] = z; }
  gemm_tile(Ag, 512, Bg, 512, 4, lds, lds + 16384, acc, wm, wn, lane, tid);
  int b = tm >> 2;
  int node_base = ((tm & 3) * 128) + wm * 64;
  int h_base = tn * 128 + wn * 64;
#pragma unroll
  for (int m = 0; m < 4; ++m) {
    int node = node_base + m * 16 + ((lane >> 4) << 2);
#pragma unroll
    for (int n = 0; n < 4; ++n) {
      int h = h_base + n * 16 + (lane & 15);
      f32x4 v = acc[m][n];
      ushort4 p;
      p.x = f2bf(v[0]); p.y = f2bf(v[1]); p.z = f2bf(v[2]); p.w = f2bf(v[3]);
      *(ushort4*)(Zt + ((size_t)b * 256 + h) * 512 + node) = p;
    }
  }
}

// ---------------------------------------------------------------------------
// Tail (one block per batch-block b):
//   y = a0n @ X2_b (bf16 in, fp32 acc); x3 = relu(y @ W2); out = x3 @ Wout
__global__ __launch_bounds__(256) void k_tail(const unsigned short* __restrict__ adjN,
                                              const unsigned short* __restrict__ X2,
                                              const float* __restrict__ W2,
                                              const float* __restrict__ Wout,
                                              float* __restrict__ out) {
  __shared__ float aL[512];
  __shared__ float yL[8][256];
  __shared__ float y[256];
  __shared__ float x3[256];
  int b = blockIdx.x, tid = threadIdx.x;
  {
    const unsigned short* a0 = adjN + (size_t)b * 512 * 512;  // row 0 of block b
    ushort2 v = ((const ushort2*)a0)[tid];
    aL[tid * 2] = bf2f(v.x);
    aL[tid * 2 + 1] = bf2f(v.y);
  }
  __syncthreads();
  {
    int hg = tid & 31, jg = tid >> 5;
    float acc8[8] = {0.f, 0.f, 0.f, 0.f, 0.f, 0.f, 0.f, 0.f};
    const unsigned short* Xb = X2 + (size_t)b * 512 * 256;
    for (int jj = 0; jj < 64; ++jj) {
      int j = jj * 8 + jg;
      short8 xv = *(const short8*)(Xb + (size_t)j * 256 + hg * 8);
      float a = aL[j];
#pragma unroll
      for (int r = 0; r < 8; ++r) acc8[r] += a * bf2f((unsigned short)xv[r]);
    }
#pragma unroll
    for (int r = 0; r < 8; ++r) yL[jg][hg * 8 + r] = acc8[r];
  }
  __syncthreads();
  {
    float s = 0.f;
#pragma unroll
    for (int g = 0; g < 8; ++g) s += yL[g][tid];
    y[tid] = s;
  }
  __syncthreads();
  {
    float s = 0.f;
    for (int k = 0; k < 256; ++k) s += y[k] * W2[(size_t)k * 256 + tid];
    x3[tid] = s > 0.f ? s : 0.f;
  }
  __syncthreads();
  if (tid < 128) {
    float s = 0.f;
    for (int h = 0; h < 256; ++h) s += x3[h] * Wout[(size_t)h * 128 + tid];
    out[(size_t)b * 128 + tid] = s;
  }
}

// ---------------------------------------------------------------------------
extern "C" void kernel_launch(void* const* d_in, const int* in_sizes, int n_in,
                              void* d_out, int out_size, void* d_ws, size_t ws_size,
                              hipStream_t stream) {
  (void)in_sizes; (void)n_in; (void)out_size; (void)ws_size;
  const float* feat = (const float*)d_in[0];
  const float* adj  = (const float*)d_in[1];
  const float* W0   = (const float*)d_in[2];
  const float* W1   = (const float*)d_in[3];
  const float* W2   = (const float*)d_in[4];
  const float* Wout = (const float*)d_in[5];
  float* out = (float*)d_out;

  char* ws = (char*)d_ws;
  unsigned short* adjN = (unsigned short*)(ws);                 // 134217728 B
  unsigned short* Xbuf = (unsigned short*)(ws + 134217728);     //  67108864 B
  unsigned short* Zt   = (unsigned short*)(ws + 201326592);     //  67108864 B
  float* nzbuf         = (float*)(ws + 268435456);              //    524288 B
  unsigned short* Wt   = (unsigned short*)(ws + 268959744);     //    262144 B

  k_wconv<<<512, 256, 0, stream>>>(W0, W1, Wt);
  // step 0 linear (fused feat conversion, also writes nz)
  k_lin0<<<2048, 256, 0, stream>>>(feat, Wt, Zt, nzbuf);
  // adjacency conversion + normalization (needs nz)
  k_adj<<<32768, 256, 0, stream>>>(adj, nzbuf, adjN);
  // step 0 propagation
  k_prop<<<2048, 256, 0, stream>>>(adjN, Zt, Xbuf);
  // step 1
  k_linear<<<2048, 256, 0, stream>>>(Xbuf, Wt + 65536, Zt);
  k_prop<<<2048, 256, 0, stream>>>(adjN, Zt, Xbuf);
  // step 2 (linear folded into tail via associativity) + output projection
  k_tail<<<256, 256, 0, stream>>>(adjN, Xbuf, W2, Wout, out);
}

// Round 7
// 315.024 us; speedup vs baseline: 1.4345x; 1.0863x over previous
//
#include <hip/hip_runtime.h>

// GCN: B=256 blocks, N=512 nodes, D_IN=D_HID=256, D_OUT=128, 3 steps.
// Round-7: R6 dataflow + (a) 2-phase double-buffered GEMM mainloop
// (STAGE(kt+1) issued BEFORE compute(kt), ONE barrier/kt -> drain covered),
// (b) prop1 fused with tail's y=a0.X2 reduction (X2 never materialized).
//   k_wconv : W0,W1 -> bf16 transposed
//   k_lin0  : Z0 = bf16(feat) @ W0 (+nz)           [unchanged from R6]
//   k_adj   : adj fp32 -> adjN bf16 pre-normalized [unchanged, BW-peak]
//   k_prop  : X1 = relu(adjN @ Z0)      [dbuf mainloop]
//   k_linear: Z1 = X1 @ W1              [dbuf mainloop]
//   k_propy : yws = per-tile a0 . relu(adjN @ Z1)  [dbuf + fused reduction]
//   k_tail  : out = relu(y @ W2) @ Wout (y from yws, 1 MB)

typedef __attribute__((ext_vector_type(8))) short short8;
typedef __attribute__((ext_vector_type(4))) float f32x4;

__device__ __forceinline__ unsigned short f2bf(float x) {
  unsigned u = __float_as_uint(x);
  unsigned r = u + 0x7fffu + ((u >> 16) & 1u);
  return (unsigned short)(r >> 16);
}
__device__ __forceinline__ float bf2f(unsigned short b) {
  return __uint_as_float(((unsigned)b) << 16);
}
__device__ __forceinline__ unsigned pkbf(float lo, float hi) {
  unsigned r;
  asm("v_cvt_pk_bf16_f32 %0, %1, %2" : "=v"(r) : "v"(lo), "v"(hi));
  return r;
}

#define GLDS(g, l) __builtin_amdgcn_global_load_lds( \
    (const __attribute__((address_space(1))) void*)(g), \
    (__attribute__((address_space(3))) void*)(l), 16, 0, 0)

// XCD-chunked bijective swizzle for grid 2048 (cpx = 256, 8 XCDs)
__device__ __forceinline__ int swz2048(int bid) { return (bid & 7) * 256 + (bid >> 3); }

// ---------------------------------------------------------------------------
__global__ void k_wconv(const float* __restrict__ W0, const float* __restrict__ W1,
                        unsigned short* __restrict__ Wt) {
  int s = blockIdx.x >> 8;
  int n = blockIdx.x & 255;
  int k = threadIdx.x;
  const float* W = s ? W1 : W0;
  Wt[(size_t)s * 65536 + n * 256 + k] = f2bf(W[(size_t)k * 256 + n]);
}

// ---------------------------------------------------------------------------
// raw_adj fp32 -> adjN bf16 normalized (rowsum over nz columns; 0 -> 1)
__global__ void k_adj(const float* __restrict__ adj, const float* __restrict__ nz,
                      unsigned short* __restrict__ adjN) {
  int row = blockIdx.x * 4 + (threadIdx.x >> 6);
  int lane = threadIdx.x & 63;
  int b = row >> 9;
  const float4* src = (const float4*)(adj + (size_t)row * 512);
  float4 a0 = src[lane * 2], a1 = src[lane * 2 + 1];
  const float4* nzp = (const float4*)(nz + (size_t)b * 512);
  float4 z0 = nzp[lane * 2], z1 = nzp[lane * 2 + 1];
  float s = a0.x * z0.x + a0.y * z0.y + a0.z * z0.z + a0.w * z0.w
          + a1.x * z1.x + a1.y * z1.y + a1.z * z1.z + a1.w * z1.w;
#pragma unroll
  for (int off = 1; off < 64; off <<= 1) s += __shfl_xor(s, off);
  float inv = 1.f / ((s == 0.f) ? 1.f : s);
  uint4 p;
  p.x = pkbf(a0.x * inv, a0.y * inv);
  p.y = pkbf(a0.z * inv, a0.w * inv);
  p.z = pkbf(a1.x * inv, a1.y * inv);
  p.w = pkbf(a1.z * inv, a1.w * inv);
  ((uint4*)(adjN + (size_t)row * 512))[lane] = p;
}

// ---------------------------------------------------------------------------
// 2-phase double-buffered MFMA mainloop (128x128 tile, BK=64, 4 waves 2x2).
// lds layout: [0,32K) = A bufs (2 x 16K), [32K,64K) = B bufs (2 x 16K).
// Per kt: STAGE(kt+1) issued FIRST, compute(kt), ONE __syncthreads() —
// the barrier's vmcnt(0) drain lands after a full compute phase.
__device__ __forceinline__ void gemm_dbuf(
    const char* Ag, int ldaB, const char* Bg, int ldbB, int nkt,
    char* lds, f32x4 acc[4][4], int wm, int wn, int lane, int tid) {
  char* ldsA = lds;
  char* ldsB = lds + 32768;
#define STAGE_AB(KT, BUF) do {                                           \
    _Pragma("unroll")                                                    \
    for (int q = 0; q < 4; ++q) {                                        \
      int P = (q * 256 + tid) * 16;                                      \
      int L = P ^ (((P >> 7) & 7) << 4);                                 \
      int row = L >> 7, cb = L & 127;                                    \
      GLDS(Ag + (size_t)row * ldaB + (KT) * 128 + cb,                    \
           ldsA + (BUF) * 16384 + P);                                    \
      GLDS(Bg + (size_t)row * ldbB + (KT) * 128 + cb,                    \
           ldsB + (BUF) * 16384 + P);                                    \
    } } while (0)
  STAGE_AB(0, 0);
  __syncthreads();                 // prologue drain (once)
  for (int kt = 0; kt < nkt; ++kt) {
    int cur = kt & 1;
    if (kt + 1 < nkt) STAGE_AB(kt + 1, cur ^ 1);   // issue next tile first
#pragma unroll
    for (int ks = 0; ks < 2; ++ks) {
      short8 af[4], bfr[4];
      int c = ks * 64 + ((lane >> 4) << 4);
#pragma unroll
      for (int m = 0; m < 4; ++m) {
        int row = wm * 64 + m * 16 + (lane & 15);
        af[m] = *(const short8*)(ldsA + cur * 16384 + ((row * 128 + c) ^ ((row & 7) << 4)));
      }
#pragma unroll
      for (int n = 0; n < 4; ++n) {
        int row = wn * 64 + n * 16 + (lane & 15);
        bfr[n] = *(const short8*)(ldsB + cur * 16384 + ((row * 128 + c) ^ ((row & 7) << 4)));
      }
#pragma unroll
      for (int m = 0; m < 4; ++m)
#pragma unroll
        for (int n = 0; n < 4; ++n)
          acc[m][n] = __builtin_amdgcn_mfma_f32_16x16x32_bf16(af[m], bfr[n], acc[m][n], 0, 0, 0);
    }
    __syncthreads();               // drains STAGE(kt+1) + guards buffer swap
  }
#undef STAGE_AB
}

// ---------------------------------------------------------------------------
// Z0 = bf16(feat) @ W0, Zt transposed out; nz in-staging (unchanged from R6).
__global__ __launch_bounds__(256) void k_lin0(const float* __restrict__ feat,
                                              const unsigned short* __restrict__ Wt,
                                              unsigned short* __restrict__ Zt,
                                              float* __restrict__ nzOut) {
  __shared__ char ldsA[16384];
  __shared__ char ldsB[16384];
  int tid = threadIdx.x, lane = tid & 63, wid = tid >> 6;
  int wm = wid >> 1, wn = wid & 1;
  int tile = swz2048(blockIdx.x);
  int tm = tile >> 1, tn = tile & 1;
  const float* Ag = feat + (size_t)tm * 128 * 256;
  const char* Bg = (const char*)(Wt + (size_t)tn * 128 * 256);
  int r = tid >> 1, hk = tid & 1;
  const float* myrow = Ag + (size_t)r * 256 + hk * 32;
  float ssq = 0.f;
  f32x4 acc[4][4];
#pragma unroll
  for (int m = 0; m < 4; ++m)
#pragma unroll
    for (int n = 0; n < 4; ++n) { f32x4 z = {0.f, 0.f, 0.f, 0.f}; acc[m][n] = z; }

  for (int kt = 0; kt < 4; ++kt) {
#pragma unroll
    for (int q = 0; q < 4; ++q) {
      int P = (q * 256 + tid) * 16;
      int L = P ^ (((P >> 7) & 7) << 4);
      int row = L >> 7, cb = L & 127;
      GLDS(Bg + (size_t)row * 512 + kt * 128 + cb, ldsB + P);
    }
    float4 f[8];
#pragma unroll
    for (int q = 0; q < 8; ++q) f[q] = ((const float4*)(myrow + kt * 64))[q];
#pragma unroll
    for (int q = 0; q < 8; ++q)
      ssq += f[q].x * f[q].x + f[q].y * f[q].y + f[q].z * f[q].z + f[q].w * f[q].w;
#pragma unroll
    for (int q = 0; q < 4; ++q) {
      uint4 w;
      w.x = pkbf(f[2 * q].x, f[2 * q].y);
      w.y = pkbf(f[2 * q].z, f[2 * q].w);
      w.z = pkbf(f[2 * q + 1].x, f[2 * q + 1].y);
      w.w = pkbf(f[2 * q + 1].z, f[2 * q + 1].w);
      int cb = hk * 64 + q * 16;
      *(uint4*)(ldsA + ((r * 128 + cb) ^ ((r & 7) << 4))) = w;
    }
    __syncthreads();
#pragma unroll
    for (int ks = 0; ks < 2; ++ks) {
      short8 af[4], bfr[4];
      int c = ks * 64 + ((lane >> 4) << 4);
#pragma unroll
      for (int m = 0; m < 4; ++m) {
        int row = wm * 64 + m * 16 + (lane & 15);
        af[m] = *(const short8*)(ldsA + ((row * 128 + c) ^ ((row & 7) << 4)));
      }
#pragma unroll
      for (int n = 0; n < 4; ++n) {
        int row = wn * 64 + n * 16 + (lane & 15);
        bfr[n] = *(const short8*)(ldsB + ((row * 128 + c) ^ ((row & 7) << 4)));
      }
#pragma unroll
      for (int m = 0; m < 4; ++m)
#pragma unroll
        for (int n = 0; n < 4; ++n)
          acc[m][n] = __builtin_amdgcn_mfma_f32_16x16x32_bf16(af[m], bfr[n], acc[m][n], 0, 0, 0);
    }
    __syncthreads();
  }

  float tot = ssq + __shfl_xor(ssq, 1);
  if (hk == 0 && tn == 0) nzOut[(size_t)tm * 128 + r] = (tot > 0.f) ? 1.f : 0.f;

  int b = tm >> 2;
  int node_base = ((tm & 3) * 128) + wm * 64;
  int h_base = tn * 128 + wn * 64;
#pragma unroll
  for (int m = 0; m < 4; ++m) {
    int node = node_base + m * 16 + ((lane >> 4) << 2);
#pragma unroll
    for (int n = 0; n < 4; ++n) {
      int h = h_base + n * 16 + (lane & 15);
      f32x4 v = acc[m][n];
      ushort4 p;
      p.x = f2bf(v[0]); p.y = f2bf(v[1]); p.z = f2bf(v[2]); p.w = f2bf(v[3]);
      *(ushort4*)(Zt + ((size_t)b * 256 + h) * 512 + node) = p;
    }
  }
}

// ---------------------------------------------------------------------------
// X = relu(adjN[b] @ Z[b]) (M=512,N=256,K=512 per block). dbuf loop. grid=2048.
__global__ __launch_bounds__(256) void k_prop(const unsigned short* __restrict__ adjN,
                                              const unsigned short* __restrict__ Zt,
                                              unsigned short* __restrict__ Xout) {
  __shared__ char lds[65536];
  int tid = threadIdx.x, lane = tid & 63, wid = tid >> 6;
  int wm = wid >> 1, wn = wid & 1;
  int tile = swz2048(blockIdx.x);
  int b = tile >> 3, tm = (tile >> 1) & 3, tn = tile & 1;
  const char* Ag = (const char*)(adjN + ((size_t)b * 512 + tm * 128) * 512);
  const char* Bg = (const char*)(Zt + ((size_t)b * 256 + tn * 128) * 512);
  f32x4 acc[4][4];
#pragma unroll
  for (int m = 0; m < 4; ++m)
#pragma unroll
    for (int n = 0; n < 4; ++n) { f32x4 z = {0.f, 0.f, 0.f, 0.f}; acc[m][n] = z; }
  gemm_dbuf(Ag, 1024, Bg, 1024, 8, lds, acc, wm, wn, lane, tid);
  int node_base = tm * 128 + wm * 64;
  int h_base = tn * 128 + wn * 64;
#pragma unroll
  for (int m = 0; m < 4; ++m) {
    int node = node_base + m * 16 + ((lane >> 4) << 2);
#pragma unroll
    for (int n = 0; n < 4; ++n) {
      int h = h_base + n * 16 + (lane & 15);
#pragma unroll
      for (int r = 0; r < 4; ++r) {
        float v = acc[m][n][r];
        v = v > 0.f ? v : 0.f;
        Xout[((size_t)b * 512 + node + r) * 256 + h] = f2bf(v);
      }
    }
  }
}

// ---------------------------------------------------------------------------
// Fused prop1 + y-reduction: yws[b][tm][h] = sum_{nodes in tile} a0n[node] *
// relu((adjN @ Z1)[node][h]).  X2 never materialized. grid = 2048.
__global__ __launch_bounds__(256) void k_propy(const unsigned short* __restrict__ adjN,
                                               const unsigned short* __restrict__ Zt,
                                               float* __restrict__ yws) {
  __shared__ char lds[65536];
  __shared__ float ybuf[2][128];
  int tid = threadIdx.x, lane = tid & 63, wid = tid >> 6;
  int wm = wid >> 1, wn = wid & 1;
  int tile = swz2048(blockIdx.x);
  int b = tile >> 3, tm = (tile >> 1) & 3, tn = tile & 1;
  const char* Ag = (const char*)(adjN + ((size_t)b * 512 + tm * 128) * 512);
  const char* Bg = (const char*)(Zt + ((size_t)b * 256 + tn * 128) * 512);
  f32x4 acc[4][4];
#pragma unroll
  for (int m = 0; m < 4; ++m)
#pragma unroll
    for (int n = 0; n < 4; ++n) { f32x4 z = {0.f, 0.f, 0.f, 0.f}; acc[m][n] = z; }
  gemm_dbuf(Ag, 1024, Bg, 1024, 8, lds, acc, wm, wn, lane, tid);

  int kq = lane >> 4, r0 = lane & 15;
  float yp[4] = {0.f, 0.f, 0.f, 0.f};
#pragma unroll
  for (int m = 0; m < 4; ++m) {
    int node = tm * 128 + wm * 64 + m * 16 + kq * 4;
    ushort4 a4 = *(const ushort4*)(adjN + (size_t)b * 262144 + node);  // row 0
    float a[4] = {bf2f(a4.x), bf2f(a4.y), bf2f(a4.z), bf2f(a4.w)};
#pragma unroll
    for (int n = 0; n < 4; ++n)
#pragma unroll
      for (int r = 0; r < 4; ++r) {
        float v = acc[m][n][r];
        v = v > 0.f ? v : 0.f;
        yp[n] += v * a[r];
      }
  }
#pragma unroll
  for (int n = 0; n < 4; ++n) {
    yp[n] += __shfl_xor(yp[n], 16);
    yp[n] += __shfl_xor(yp[n], 32);
  }
  if (lane < 16) {
#pragma unroll
    for (int n = 0; n < 4; ++n) ybuf[wm][wn * 64 + n * 16 + lane] = yp[n];
  }
  __syncthreads();
  if (tid < 128)
    yws[((size_t)b * 4 + tm) * 256 + tn * 128 + tid] = ybuf[0][tid] + ybuf[1][tid];
}

// ---------------------------------------------------------------------------
// Z = X @ W (M=131072,N=256,K=256), Zt transposed out. dbuf loop. grid=2048.
__global__ __launch_bounds__(256) void k_linear(const unsigned short* __restrict__ X,
                                                const unsigned short* __restrict__ Wt,
                                                unsigned short* __restrict__ Zt) {
  __shared__ char lds[65536];
  int tid = threadIdx.x, lane = tid & 63, wid = tid >> 6;
  int wm = wid >> 1, wn = wid & 1;
  int tile = swz2048(blockIdx.x);
  int tm = tile >> 1, tn = tile & 1;
  const char* Ag = (const char*)(X + (size_t)tm * 128 * 256);
  const char* Bg = (const char*)(Wt + (size_t)tn * 128 * 256);
  f32x4 acc[4][4];
#pragma unroll
  for (int m = 0; m < 4; ++m)
#pragma unroll
    for (int n = 0; n < 4; ++n) { f32x4 z = {0.f, 0.f, 0.f, 0.f}; acc[m][n] = z; }
  gemm_dbuf(Ag, 512, Bg, 512, 4, lds, acc, wm, wn, lane, tid);
  int b = tm >> 2;
  int node_base = ((tm & 3) * 128) + wm * 64;
  int h_base = tn * 128 + wn * 64;
#pragma unroll
  for (int m = 0; m < 4; ++m) {
    int node = node_base + m * 16 + ((lane >> 4) << 2);
#pragma unroll
    for (int n = 0; n < 4; ++n) {
      int h = h_base + n * 16 + (lane & 15);
      f32x4 v = acc[m][n];
      ushort4 p;
      p.x = f2bf(v[0]); p.y = f2bf(v[1]); p.z = f2bf(v[2]); p.w = f2bf(v[3]);
      *(ushort4*)(Zt + ((size_t)b * 256 + h) * 512 + node) = p;
    }
  }
}

// ---------------------------------------------------------------------------
// Tail: y[h] = sum_tm yws[b][tm][h]; x3 = relu(y @ W2); out = x3 @ Wout.
__global__ __launch_bounds__(256) void k_tail(const float* __restrict__ yws,
                                              const float* __restrict__ W2,
                                              const float* __restrict__ Wout,
                                              float* __restrict__ out) {
  __shared__ float y[256];
  __shared__ float x3[256];
  int b = blockIdx.x, tid = threadIdx.x;
  const float* w = yws + (size_t)b * 1024;
  y[tid] = w[tid] + w[256 + tid] + w[512 + tid] + w[768 + tid];
  __syncthreads();
  {
    float s = 0.f;
    for (int k = 0; k < 256; ++k) s += y[k] * W2[(size_t)k * 256 + tid];
    x3[tid] = s > 0.f ? s : 0.f;
  }
  __syncthreads();
  if (tid < 128) {
    float s = 0.f;
    for (int h = 0; h < 256; ++h) s += x3[h] * Wout[(size_t)h * 128 + tid];
    out[(size_t)b * 128 + tid] = s;
  }
}

// ---------------------------------------------------------------------------
extern "C" void kernel_launch(void* const* d_in, const int* in_sizes, int n_in,
                              void* d_out, int out_size, void* d_ws, size_t ws_size,
                              hipStream_t stream) {
  (void)in_sizes; (void)n_in; (void)out_size; (void)ws_size;
  const float* feat = (const float*)d_in[0];
  const float* adj  = (const float*)d_in[1];
  const float* W0   = (const float*)d_in[2];
  const float* W1   = (const float*)d_in[3];
  const float* W2   = (const float*)d_in[4];
  const float* Wout = (const float*)d_in[5];
  float* out = (float*)d_out;

  char* ws = (char*)d_ws;
  unsigned short* adjN = (unsigned short*)(ws);                 // 134217728 B
  unsigned short* Xbuf = (unsigned short*)(ws + 134217728);     //  67108864 B
  unsigned short* Zt   = (unsigned short*)(ws + 201326592);     //  67108864 B
  float* nzbuf         = (float*)(ws + 268435456);              //    524288 B
  unsigned short* Wt   = (unsigned short*)(ws + 268959744);     //    262144 B
  float* yws           = (float*)(ws + 269221888);              //   1048576 B

  k_wconv<<<512, 256, 0, stream>>>(W0, W1, Wt);
  // step 0 linear (fused feat conversion, also writes nz)
  k_lin0<<<2048, 256, 0, stream>>>(feat, Wt, Zt, nzbuf);
  // adjacency conversion + normalization (needs nz)
  k_adj<<<32768, 256, 0, stream>>>(adj, nzbuf, adjN);
  // step 0 propagation
  k_prop<<<2048, 256, 0, stream>>>(adjN, Zt, Xbuf);
  // step 1 linear
  k_linear<<<2048, 256, 0, stream>>>(Xbuf, Wt + 65536, Zt);
  // step 1 propagation fused with tail's y-reduction (X2 never written)
  k_propy<<<2048, 256, 0, stream>>>(adjN, Zt, yws);
  // step 2 tail: relu(y @ W2) @ Wout
  k_tail<<<256, 256, 0, stream>>>(yws, W2, Wout, out);
}

// Round 8
// 313.304 us; speedup vs baseline: 1.4424x; 1.0055x over previous
//
#include <hip/hip_runtime.h>

// GCN: B=256 blocks, N=512 nodes, D_IN=D_HID=256, D_OUT=128, 3 steps.
// Round-8: R7 + double-buffered k_lin0 (issue-early/write-late A staging).
//   k_wconv : W0,W1 -> bf16 transposed
//   k_lin0  : Z0 = bf16(feat) @ W0 (+nz)  [NEW: 2-phase dbuf + T14 split]
//   k_adj   : adj fp32 -> adjN bf16 pre-normalized (BW-floor)
//   k_prop  : X1 = relu(adjN @ Z0)        [dbuf]
//   k_linear: Z1 = X1 @ W1                [dbuf]
//   k_propy : yws = per-tile a0 . relu(adjN @ Z1)  [dbuf + fused reduction]
//   k_tail  : out = relu(y @ W2) @ Wout

typedef __attribute__((ext_vector_type(8))) short short8;
typedef __attribute__((ext_vector_type(4))) float f32x4;

__device__ __forceinline__ unsigned short f2bf(float x) {
  unsigned u = __float_as_uint(x);
  unsigned r = u + 0x7fffu + ((u >> 16) & 1u);
  return (unsigned short)(r >> 16);
}
__device__ __forceinline__ float bf2f(unsigned short b) {
  return __uint_as_float(((unsigned)b) << 16);
}
__device__ __forceinline__ unsigned pkbf(float lo, float hi) {
  unsigned r;
  asm("v_cvt_pk_bf16_f32 %0, %1, %2" : "=v"(r) : "v"(lo), "v"(hi));
  return r;
}

#define GLDS(g, l) __builtin_amdgcn_global_load_lds( \
    (const __attribute__((address_space(1))) void*)(g), \
    (__attribute__((address_space(3))) void*)(l), 16, 0, 0)

// XCD-chunked bijective swizzle for grid 2048 (cpx = 256, 8 XCDs)
__device__ __forceinline__ int swz2048(int bid) { return (bid & 7) * 256 + (bid >> 3); }

// ---------------------------------------------------------------------------
__global__ void k_wconv(const float* __restrict__ W0, const float* __restrict__ W1,
                        unsigned short* __restrict__ Wt) {
  int s = blockIdx.x >> 8;
  int n = blockIdx.x & 255;
  int k = threadIdx.x;
  const float* W = s ? W1 : W0;
  Wt[(size_t)s * 65536 + n * 256 + k] = f2bf(W[(size_t)k * 256 + n]);
}

// ---------------------------------------------------------------------------
// raw_adj fp32 -> adjN bf16 normalized (rowsum over nz columns; 0 -> 1)
__global__ void k_adj(const float* __restrict__ adj, const float* __restrict__ nz,
                      unsigned short* __restrict__ adjN) {
  int row = blockIdx.x * 4 + (threadIdx.x >> 6);
  int lane = threadIdx.x & 63;
  int b = row >> 9;
  const float4* src = (const float4*)(adj + (size_t)row * 512);
  float4 a0 = src[lane * 2], a1 = src[lane * 2 + 1];
  const float4* nzp = (const float4*)(nz + (size_t)b * 512);
  float4 z0 = nzp[lane * 2], z1 = nzp[lane * 2 + 1];
  float s = a0.x * z0.x + a0.y * z0.y + a0.z * z0.z + a0.w * z0.w
          + a1.x * z1.x + a1.y * z1.y + a1.z * z1.z + a1.w * z1.w;
#pragma unroll
  for (int off = 1; off < 64; off <<= 1) s += __shfl_xor(s, off);
  float inv = 1.f / ((s == 0.f) ? 1.f : s);
  uint4 p;
  p.x = pkbf(a0.x * inv, a0.y * inv);
  p.y = pkbf(a0.z * inv, a0.w * inv);
  p.z = pkbf(a1.x * inv, a1.y * inv);
  p.w = pkbf(a1.z * inv, a1.w * inv);
  ((uint4*)(adjN + (size_t)row * 512))[lane] = p;
}

// ---------------------------------------------------------------------------
// 2-phase double-buffered MFMA mainloop (128x128 tile, BK=64, 4 waves 2x2).
__device__ __forceinline__ void gemm_dbuf(
    const char* Ag, int ldaB, const char* Bg, int ldbB, int nkt,
    char* lds, f32x4 acc[4][4], int wm, int wn, int lane, int tid) {
  char* ldsA = lds;
  char* ldsB = lds + 32768;
#define STAGE_AB(KT, BUF) do {                                           \
    _Pragma("unroll")                                                    \
    for (int q = 0; q < 4; ++q) {                                        \
      int P = (q * 256 + tid) * 16;                                      \
      int L = P ^ (((P >> 7) & 7) << 4);                                 \
      int row = L >> 7, cb = L & 127;                                    \
      GLDS(Ag + (size_t)row * ldaB + (KT) * 128 + cb,                    \
           ldsA + (BUF) * 16384 + P);                                    \
      GLDS(Bg + (size_t)row * ldbB + (KT) * 128 + cb,                    \
           ldsB + (BUF) * 16384 + P);                                    \
    } } while (0)
  STAGE_AB(0, 0);
  __syncthreads();
  for (int kt = 0; kt < nkt; ++kt) {
    int cur = kt & 1;
    if (kt + 1 < nkt) STAGE_AB(kt + 1, cur ^ 1);   // issue next tile first
#pragma unroll
    for (int ks = 0; ks < 2; ++ks) {
      short8 af[4], bfr[4];
      int c = ks * 64 + ((lane >> 4) << 4);
#pragma unroll
      for (int m = 0; m < 4; ++m) {
        int row = wm * 64 + m * 16 + (lane & 15);
        af[m] = *(const short8*)(ldsA + cur * 16384 + ((row * 128 + c) ^ ((row & 7) << 4)));
      }
#pragma unroll
      for (int n = 0; n < 4; ++n) {
        int row = wn * 64 + n * 16 + (lane & 15);
        bfr[n] = *(const short8*)(ldsB + cur * 16384 + ((row * 128 + c) ^ ((row & 7) << 4)));
      }
#pragma unroll
      for (int m = 0; m < 4; ++m)
#pragma unroll
        for (int n = 0; n < 4; ++n)
          acc[m][n] = __builtin_amdgcn_mfma_f32_16x16x32_bf16(af[m], bfr[n], acc[m][n], 0, 0, 0);
    }
    __syncthreads();
  }
#undef STAGE_AB
}

// ---------------------------------------------------------------------------
// Z0 = bf16(feat) @ W0, Zt transposed out; nz in-staging.
// NEW: double-buffered A (reg-staged fp32, issue-early/write-late) + B (GLDS).
__global__ __launch_bounds__(256) void k_lin0(const float* __restrict__ feat,
                                              const unsigned short* __restrict__ Wt,
                                              unsigned short* __restrict__ Zt,
                                              float* __restrict__ nzOut) {
  __shared__ char ldsA[32768];   // 2 x 16 KB
  __shared__ char ldsB[32768];   // 2 x 16 KB
  int tid = threadIdx.x, lane = tid & 63, wid = tid >> 6;
  int wm = wid >> 1, wn = wid & 1;
  int tile = swz2048(blockIdx.x);
  int tm = tile >> 1, tn = tile & 1;
  const float* Ag = feat + (size_t)tm * 128 * 256;
  const char* Bg = (const char*)(Wt + (size_t)tn * 128 * 256);
  int r = tid >> 1, hk = tid & 1;
  const float* myrow = Ag + (size_t)r * 256 + hk * 32;
  float ssq = 0.f;
  f32x4 acc[4][4];
#pragma unroll
  for (int m = 0; m < 4; ++m)
#pragma unroll
    for (int n = 0; n < 4; ++n) { f32x4 z = {0.f, 0.f, 0.f, 0.f}; acc[m][n] = z; }

#define L0_STAGE_B(KT, BUF) do {                                         \
    _Pragma("unroll")                                                    \
    for (int q = 0; q < 4; ++q) {                                        \
      int P = (q * 256 + tid) * 16;                                      \
      int L = P ^ (((P >> 7) & 7) << 4);                                 \
      int row = L >> 7, cb = L & 127;                                    \
      GLDS(Bg + (size_t)row * 512 + (KT) * 128 + cb,                     \
           ldsB + (BUF) * 16384 + P);                                    \
    } } while (0)
#define L0_LOAD_A(KT) do {                                               \
    _Pragma("unroll")                                                    \
    for (int q = 0; q < 8; ++q)                                          \
      fA[q] = ((const float4*)(myrow + (KT) * 64))[q];                   \
    } while (0)
#define L0_WRITE_A(BUF) do {                                             \
    _Pragma("unroll")                                                    \
    for (int q = 0; q < 8; ++q)                                          \
      ssq += fA[q].x * fA[q].x + fA[q].y * fA[q].y                       \
           + fA[q].z * fA[q].z + fA[q].w * fA[q].w;                      \
    _Pragma("unroll")                                                    \
    for (int q = 0; q < 4; ++q) {                                        \
      uint4 w;                                                           \
      w.x = pkbf(fA[2 * q].x, fA[2 * q].y);                              \
      w.y = pkbf(fA[2 * q].z, fA[2 * q].w);                              \
      w.z = pkbf(fA[2 * q + 1].x, fA[2 * q + 1].y);                      \
      w.w = pkbf(fA[2 * q + 1].z, fA[2 * q + 1].w);                      \
      int cb = hk * 64 + q * 16;                                         \
      *(uint4*)(ldsA + (BUF) * 16384 +                                   \
                ((r * 128 + cb) ^ ((r & 7) << 4))) = w;                  \
    } } while (0)

  float4 fA[8];
  // prologue: stage kt=0 into buf 0
  L0_LOAD_A(0);
  L0_STAGE_B(0, 0);
  L0_WRITE_A(0);
  __syncthreads();

#pragma unroll
  for (int kt = 0; kt < 4; ++kt) {
    int cur = kt & 1;
    if (kt < 3) {
      L0_LOAD_A(kt + 1);          // issue early (lands during compute)
      L0_STAGE_B(kt + 1, cur ^ 1);
    }
#pragma unroll
    for (int ks = 0; ks < 2; ++ks) {
      short8 af[4], bfr[4];
      int c = ks * 64 + ((lane >> 4) << 4);
#pragma unroll
      for (int m = 0; m < 4; ++m) {
        int row = wm * 64 + m * 16 + (lane & 15);
        af[m] = *(const short8*)(ldsA + cur * 16384 + ((row * 128 + c) ^ ((row & 7) << 4)));
      }
#pragma unroll
      for (int n = 0; n < 4; ++n) {
        int row = wn * 64 + n * 16 + (lane & 15);
        bfr[n] = *(const short8*)(ldsB + cur * 16384 + ((row * 128 + c) ^ ((row & 7) << 4)));
      }
#pragma unroll
      for (int m = 0; m < 4; ++m)
#pragma unroll
        for (int n = 0; n < 4; ++n)
          acc[m][n] = __builtin_amdgcn_mfma_f32_16x16x32_bf16(af[m], bfr[n], acc[m][n], 0, 0, 0);
    }
    if (kt < 3) L0_WRITE_A(cur ^ 1);   // write late: loads have landed
    __syncthreads();
  }
#undef L0_STAGE_B
#undef L0_LOAD_A
#undef L0_WRITE_A

  float tot = ssq + __shfl_xor(ssq, 1);
  if (hk == 0 && tn == 0) nzOut[(size_t)tm * 128 + r] = (tot > 0.f) ? 1.f : 0.f;

  int b = tm >> 2;
  int node_base = ((tm & 3) * 128) + wm * 64;
  int h_base = tn * 128 + wn * 64;
#pragma unroll
  for (int m = 0; m < 4; ++m) {
    int node = node_base + m * 16 + ((lane >> 4) << 2);
#pragma unroll
    for (int n = 0; n < 4; ++n) {
      int h = h_base + n * 16 + (lane & 15);
      f32x4 v = acc[m][n];
      ushort4 p;
      p.x = f2bf(v[0]); p.y = f2bf(v[1]); p.z = f2bf(v[2]); p.w = f2bf(v[3]);
      *(ushort4*)(Zt + ((size_t)b * 256 + h) * 512 + node) = p;
    }
  }
}

// ---------------------------------------------------------------------------
// X = relu(adjN[b] @ Z[b]) (M=512,N=256,K=512 per block). dbuf loop. grid=2048.
__global__ __launch_bounds__(256) void k_prop(const unsigned short* __restrict__ adjN,
                                              const unsigned short* __restrict__ Zt,
                                              unsigned short* __restrict__ Xout) {
  __shared__ char lds[65536];
  int tid = threadIdx.x, lane = tid & 63, wid = tid >> 6;
  int wm = wid >> 1, wn = wid & 1;
  int tile = swz2048(blockIdx.x);
  int b = tile >> 3, tm = (tile >> 1) & 3, tn = tile & 1;
  const char* Ag = (const char*)(adjN + ((size_t)b * 512 + tm * 128) * 512);
  const char* Bg = (const char*)(Zt + ((size_t)b * 256 + tn * 128) * 512);
  f32x4 acc[4][4];
#pragma unroll
  for (int m = 0; m < 4; ++m)
#pragma unroll
    for (int n = 0; n < 4; ++n) { f32x4 z = {0.f, 0.f, 0.f, 0.f}; acc[m][n] = z; }
  gemm_dbuf(Ag, 1024, Bg, 1024, 8, lds, acc, wm, wn, lane, tid);
  int node_base = tm * 128 + wm * 64;
  int h_base = tn * 128 + wn * 64;
#pragma unroll
  for (int m = 0; m < 4; ++m) {
    int node = node_base + m * 16 + ((lane >> 4) << 2);
#pragma unroll
    for (int n = 0; n < 4; ++n) {
      int h = h_base + n * 16 + (lane & 15);
#pragma unroll
      for (int r = 0; r < 4; ++r) {
        float v = acc[m][n][r];
        v = v > 0.f ? v : 0.f;
        Xout[((size_t)b * 512 + node + r) * 256 + h] = f2bf(v);
      }
    }
  }
}

// ---------------------------------------------------------------------------
// Fused prop1 + y-reduction: yws[b][tm][h] = sum_{nodes in tile} a0n[node] *
// relu((adjN @ Z1)[node][h]).  X2 never materialized. grid = 2048.
__global__ __launch_bounds__(256) void k_propy(const unsigned short* __restrict__ adjN,
                                               const unsigned short* __restrict__ Zt,
                                               float* __restrict__ yws) {
  __shared__ char lds[65536];
  __shared__ float ybuf[2][128];
  int tid = threadIdx.x, lane = tid & 63, wid = tid >> 6;
  int wm = wid >> 1, wn = wid & 1;
  int tile = swz2048(blockIdx.x);
  int b = tile >> 3, tm = (tile >> 1) & 3, tn = tile & 1;
  const char* Ag = (const char*)(adjN + ((size_t)b * 512 + tm * 128) * 512);
  const char* Bg = (const char*)(Zt + ((size_t)b * 256 + tn * 128) * 512);
  f32x4 acc[4][4];
#pragma unroll
  for (int m = 0; m < 4; ++m)
#pragma unroll
    for (int n = 0; n < 4; ++n) { f32x4 z = {0.f, 0.f, 0.f, 0.f}; acc[m][n] = z; }
  gemm_dbuf(Ag, 1024, Bg, 1024, 8, lds, acc, wm, wn, lane, tid);

  int kq = lane >> 4, r0 = lane & 15;
  float yp[4] = {0.f, 0.f, 0.f, 0.f};
#pragma unroll
  for (int m = 0; m < 4; ++m) {
    int node = tm * 128 + wm * 64 + m * 16 + kq * 4;
    ushort4 a4 = *(const ushort4*)(adjN + (size_t)b * 262144 + node);  // row 0
    float a[4] = {bf2f(a4.x), bf2f(a4.y), bf2f(a4.z), bf2f(a4.w)};
#pragma unroll
    for (int n = 0; n < 4; ++n)
#pragma unroll
      for (int r = 0; r < 4; ++r) {
        float v = acc[m][n][r];
        v = v > 0.f ? v : 0.f;
        yp[n] += v * a[r];
      }
  }
#pragma unroll
  for (int n = 0; n < 4; ++n) {
    yp[n] += __shfl_xor(yp[n], 16);
    yp[n] += __shfl_xor(yp[n], 32);
  }
  if (lane < 16) {
#pragma unroll
    for (int n = 0; n < 4; ++n) ybuf[wm][wn * 64 + n * 16 + lane] = yp[n];
  }
  __syncthreads();
  if (tid < 128)
    yws[((size_t)b * 4 + tm) * 256 + tn * 128 + tid] = ybuf[0][tid] + ybuf[1][tid];
}

// ---------------------------------------------------------------------------
// Z = X @ W (M=131072,N=256,K=256), Zt transposed out. dbuf loop. grid=2048.
__global__ __launch_bounds__(256) void k_linear(const unsigned short* __restrict__ X,
                                                const unsigned short* __restrict__ Wt,
                                                unsigned short* __restrict__ Zt) {
  __shared__ char lds[65536];
  int tid = threadIdx.x, lane = tid & 63, wid = tid >> 6;
  int wm = wid >> 1, wn = wid & 1;
  int tile = swz2048(blockIdx.x);
  int tm = tile >> 1, tn = tile & 1;
  const char* Ag = (const char*)(X + (size_t)tm * 128 * 256);
  const char* Bg = (const char*)(Wt + (size_t)tn * 128 * 256);
  f32x4 acc[4][4];
#pragma unroll
  for (int m = 0; m < 4; ++m)
#pragma unroll
    for (int n = 0; n < 4; ++n) { f32x4 z = {0.f, 0.f, 0.f, 0.f}; acc[m][n] = z; }
  gemm_dbuf(Ag, 512, Bg, 512, 4, lds, acc, wm, wn, lane, tid);
  int b = tm >> 2;
  int node_base = ((tm & 3) * 128) + wm * 64;
  int h_base = tn * 128 + wn * 64;
#pragma unroll
  for (int m = 0; m < 4; ++m) {
    int node = node_base + m * 16 + ((lane >> 4) << 2);
#pragma unroll
    for (int n = 0; n < 4; ++n) {
      int h = h_base + n * 16 + (lane & 15);
      f32x4 v = acc[m][n];
      ushort4 p;
      p.x = f2bf(v[0]); p.y = f2bf(v[1]); p.z = f2bf(v[2]); p.w = f2bf(v[3]);
      *(ushort4*)(Zt + ((size_t)b * 256 + h) * 512 + node) = p;
    }
  }
}

// ---------------------------------------------------------------------------
// Tail: y[h] = sum_tm yws[b][tm][h]; x3 = relu(y @ W2); out = x3 @ Wout.
__global__ __launch_bounds__(256) void k_tail(const float* __restrict__ yws,
                                              const float* __restrict__ W2,
                                              const float* __restrict__ Wout,
                                              float* __restrict__ out) {
  __shared__ float y[256];
  __shared__ float x3[256];
  int b = blockIdx.x, tid = threadIdx.x;
  const float* w = yws + (size_t)b * 1024;
  y[tid] = w[tid] + w[256 + tid] + w[512 + tid] + w[768 + tid];
  __syncthreads();
  {
    float s = 0.f;
    for (int k = 0; k < 256; ++k) s += y[k] * W2[(size_t)k * 256 + tid];
    x3[tid] = s > 0.f ? s : 0.f;
  }
  __syncthreads();
  if (tid < 128) {
    float s = 0.f;
    for (int h = 0; h < 256; ++h) s += x3[h] * Wout[(size_t)h * 128 + tid];
    out[(size_t)b * 128 + tid] = s;
  }
}

// ---------------------------------------------------------------------------
extern "C" void kernel_launch(void* const* d_in, const int* in_sizes, int n_in,
                              void* d_out, int out_size, void* d_ws, size_t ws_size,
                              hipStream_t stream) {
  (void)in_sizes; (void)n_in; (void)out_size; (void)ws_size;
  const float* feat = (const float*)d_in[0];
  const float* adj  = (const float*)d_in[1];
  const float* W0   = (const float*)d_in[2];
  const float* W1   = (const float*)d_in[3];
  const float* W2   = (const float*)d_in[4];
  const float* Wout = (const float*)d_in[5];
  float* out = (float*)d_out;

  char* ws = (char*)d_ws;
  unsigned short* adjN = (unsigned short*)(ws);                 // 134217728 B
  unsigned short* Xbuf = (unsigned short*)(ws + 134217728);     //  67108864 B
  unsigned short* Zt   = (unsigned short*)(ws + 201326592);     //  67108864 B
  float* nzbuf         = (float*)(ws + 268435456);              //    524288 B
  unsigned short* Wt   = (unsigned short*)(ws + 268959744);     //    262144 B
  float* yws           = (float*)(ws + 269221888);              //   1048576 B

  k_wconv<<<512, 256, 0, stream>>>(W0, W1, Wt);
  // step 0 linear (fused feat conversion, also writes nz)
  k_lin0<<<2048, 256, 0, stream>>>(feat, Wt, Zt, nzbuf);
  // adjacency conversion + normalization (needs nz)
  k_adj<<<32768, 256, 0, stream>>>(adj, nzbuf, adjN);
  // step 0 propagation
  k_prop<<<2048, 256, 0, stream>>>(adjN, Zt, Xbuf);
  // step 1 linear
  k_linear<<<2048, 256, 0, stream>>>(Xbuf, Wt + 65536, Zt);
  // step 1 propagation fused with tail's y-reduction (X2 never written)
  k_propy<<<2048, 256, 0, stream>>>(adjN, Zt, yws);
  // step 2 tail: relu(y @ W2) @ Wout
  k_tail<<<256, 256, 0, stream>>>(yws, W2, Wout, out);
}